// Round 1
// 4575.442 us; speedup vs baseline: 4.0628x; 4.0628x over previous
//
#include <hip/hip_runtime.h>
#include <hip/hip_bf16.h>
#include <math.h>

// ---------------- problem constants ----------------
#define HRES   64
#define WRES   128
#define CDIM   768
#define NHEADS 8
#define WINSZ  8
#define NTOK   64          // WINSZ*WINSZ
#define HDIM   96          // CDIM/NHEADS
#define HIDDIM 3072
#define NWH    8           // HRES/WINSZ
#define NWW    16          // WRES/WINSZ
#define NWIMG  128         // NWH*NWW
#define NWTOT  512         // B*NWIMG
#define MTOT   32768       // NWTOT*NTOK
#define CPBH   512

typedef unsigned short u16;
typedef __attribute__((ext_vector_type(8))) short bf16x8;   // 8 bf16 in 4 VGPRs
typedef __attribute__((ext_vector_type(4))) float f32x4;

__device__ __forceinline__ float bf2f(u16 u) {
    return __uint_as_float(((unsigned)u) << 16);
}
__device__ __forceinline__ u16 f2bf(float f) {
    unsigned u = __float_as_uint(f);
    u += 0x7FFFu + ((u >> 16) & 1u);
    return (u16)(u >> 16);
}
__device__ __forceinline__ float gelu_exact(float x) {
    return 0.5f * x * (1.0f + erff(x * 0.70710678118654752f));
}
__device__ __forceinline__ int reg_r(int r) { return r < HRES-8 ? 0 : (r < HRES-4 ? 1 : 2); }
__device__ __forceinline__ int reg_c(int c) { return c < WRES-8 ? 0 : (c < WRES-4 ? 1 : 2); }

// ---------------- fp32 copy input -> residual X (in d_out) ----------------
__global__ __launch_bounds__(256) void k_copy(const float4* __restrict__ in,
                                              float4* __restrict__ out) {
    size_t i = (size_t)blockIdx.x * 256 + threadIdx.x;
    out[i] = in[i];
}

// ---------------- generic fp32 -> bf16 conversion (weights) ----------------
__global__ __launch_bounds__(256) void k_cvt(const float4* __restrict__ in,
                                             ushort4* __restrict__ out, int n4) {
    int i = blockIdx.x * 256 + threadIdx.x;
    if (i < n4) {
        float4 v = in[i];
        ushort4 o;
        o.x = f2bf(v.x); o.y = f2bf(v.y); o.z = f2bf(v.z); o.w = f2bf(v.w);
        out[i] = o;
    }
}

// ---------------- build combined qkv bias (q | 0 | v), fp32 ----------------
__global__ __launch_bounds__(256) void k_qkvb(const float* __restrict__ qb,
                                              const float* __restrict__ vb,
                                              float* __restrict__ dst) {
    int i = blockIdx.x * 256 + threadIdx.x;
    if (i < 2304)
        dst[i] = (i < 768) ? qb[i] : ((i < 1536) ? 0.f : vb[i - 1536]);
}

// ---------------- X rows -> bf16 rows, optional shifted-window gather ----------------
__global__ __launch_bounds__(192) void k_xcvt(const float* __restrict__ X,
                                              u16* __restrict__ out,
                                              int m0, int shift, int winmap) {
    int lm = blockIdx.x, t = threadIdx.x;
    int gm = m0 + lm;
    int src;
    if (winmap) {
        int w = gm >> 6, n = gm & 63;
        int b = w >> 7, wim = w & 127, hi = wim >> 4, wi = wim & 15;
        int p = n >> 3, q = n & 7;
        int r  = (hi * 8 + p + shift) & (HRES - 1);
        int cc = (wi * 8 + q + shift) & (WRES - 1);
        src = (b * HRES + r) * WRES + cc;
    } else {
        src = gm;
    }
    float4 v = *(const float4*)(X + (size_t)src * CDIM + t * 4);
    ushort4 o;
    o.x = f2bf(v.x); o.y = f2bf(v.y); o.z = f2bf(v.z); o.w = f2bf(v.w);
    *(ushort4*)(out + (size_t)lm * CDIM + t * 4) = o;
}

// ---------------- CPB MLP: rpb table (225 x 8) + per-head scale ----------------
__global__ __launch_bounds__(256) void k_cpb(const float* __restrict__ w1,
                                             const float* __restrict__ b1,
                                             const float* __restrict__ w2,
                                             const float* __restrict__ ls,
                                             float* __restrict__ rpb,
                                             float* __restrict__ scale) {
    int t = threadIdx.x;
    if (t < NHEADS) scale[t] = __expf(fminf(ls[t], 4.6051701859880914f)); // ln(100)
    for (int idx = t; idx < 225 * NHEADS; idx += 256) {
        int tt = idx >> 3, h = idx & 7;
        int i = tt / 15, j = tt % 15;
        float vi = 8.0f * (float)(i - 7) / 7.0f;
        float vj = 8.0f * (float)(j - 7) / 7.0f;
        float si = (vi > 0.f) ? 1.f : ((vi < 0.f) ? -1.f : 0.f);
        float sj = (vj > 0.f) ? 1.f : ((vj < 0.f) ? -1.f : 0.f);
        float c0 = si * log2f(fabsf(vi) + 1.0f) * (1.0f / 3.0f);
        float c1 = sj * log2f(fabsf(vj) + 1.0f) * (1.0f / 3.0f);
        float sum = 0.f;
        for (int k = 0; k < CPBH; ++k) {
            float hv = c0 * w1[2*k] + c1 * w1[2*k+1] + b1[k];
            if (hv > 0.f) sum += hv * w2[h * CPBH + k];
        }
        rpb[idx] = 16.0f / (1.0f + __expf(-sum));
    }
}

// ---------------- bf16 MFMA GEMM: C[M][N] = A[M][K] @ Bw[N][K]^T + bias ----------------
// 128x128 tile, 256 threads = 4 waves, each wave one 64x64 quadrant via
// mfma_f32_16x16x32_bf16 (4x4 fragments). LDS tiles row-major [128][32].
// EPI: 0 = bias store; 1 = gelu(acc+bias); 2 = C *= (acc+bias) in place.
template<int EPI>
__global__ __launch_bounds__(256) void k_mm(const u16* __restrict__ A,
                                            const u16* __restrict__ Bw,
                                            const float* __restrict__ bias,
                                            u16* __restrict__ C,
                                            int K, int N) {
    __shared__ __align__(16) u16 As[128 * 32];
    __shared__ __align__(16) u16 Bs[128 * 32];
    int t = threadIdx.x;
    int tm = blockIdx.x << 7, tn = blockIdx.y << 7;
    int l = t & 63, w = t >> 6;
    // staging: thread t loads slot t (row0, kc) and slot t+256 (row0+64, kc)
    int row0 = t >> 2, kc = t & 3;
    const u16* Ag0 = A  + (size_t)(tm + row0) * K + kc * 8;
    const u16* Ag1 = Ag0 + (size_t)64 * K;
    const u16* Bg0 = Bw + (size_t)(tn + row0) * K + kc * 8;
    const u16* Bg1 = Bg0 + (size_t)64 * K;
    // fragment coords
    int fr = l & 15, fk = l >> 4;
    int r0 = (w >> 1) << 6, c0 = (w & 1) << 6;
    f32x4 zero = {0.f, 0.f, 0.f, 0.f};
    f32x4 acc[4][4];
    #pragma unroll
    for (int i = 0; i < 4; ++i)
        #pragma unroll
        for (int j = 0; j < 4; ++j)
            acc[i][j] = zero;
    for (int k0 = 0; k0 < K; k0 += 32) {
        uint4 va0 = *(const uint4*)(Ag0 + k0);
        uint4 va1 = *(const uint4*)(Ag1 + k0);
        uint4 vb0 = *(const uint4*)(Bg0 + k0);
        uint4 vb1 = *(const uint4*)(Bg1 + k0);
        __syncthreads();                 // previous iter done reading LDS
        *(uint4*)&As[t * 8]        = va0;
        *(uint4*)&As[t * 8 + 2048] = va1;
        *(uint4*)&Bs[t * 8]        = vb0;
        *(uint4*)&Bs[t * 8 + 2048] = vb1;
        __syncthreads();
        bf16x8 Af[4], Bf[4];
        #pragma unroll
        for (int i = 0; i < 4; ++i)
            Af[i] = *(const bf16x8*)&As[((r0 + i * 16 + fr) << 5) + (fk << 3)];
        #pragma unroll
        for (int j = 0; j < 4; ++j)
            Bf[j] = *(const bf16x8*)&Bs[((c0 + j * 16 + fr) << 5) + (fk << 3)];
        #pragma unroll
        for (int i = 0; i < 4; ++i)
            #pragma unroll
            for (int j = 0; j < 4; ++j)
                acc[i][j] = __builtin_amdgcn_mfma_f32_16x16x32_bf16(Af[i], Bf[j], acc[i][j], 0, 0, 0);
    }
    // epilogue: C/D layout col = lane&15, row = (lane>>4)*4 + reg  [verified m89]
    int lr4 = fk << 2;
    #pragma unroll
    for (int j = 0; j < 4; ++j) {
        int col = tn + c0 + j * 16 + fr;
        float bj = bias[col];
        #pragma unroll
        for (int i = 0; i < 4; ++i) {
            int row = tm + r0 + i * 16 + lr4;
            #pragma unroll
            for (int r = 0; r < 4; ++r) {
                size_t idx = (size_t)(row + r) * N + col;
                float v = acc[i][j][r] + bj;
                if (EPI == 0)      C[idx] = f2bf(v);
                else if (EPI == 1) C[idx] = f2bf(gelu_exact(v));
                else               C[idx] = f2bf(bf2f(C[idx]) * v);
            }
        }
    }
}

// ---------------- fused attention per (window, head); bf16 in/out ----------------
__global__ __launch_bounds__(256) void k_attn(const u16* __restrict__ QKV,
                                              const float* __restrict__ rpb,
                                              const float* __restrict__ scale,
                                              u16* __restrict__ outw,
                                              int shift, int w0) {
    __shared__ float smQ[64][100];   // q, later reused for v (pad 100: float4-aligned rows)
    __shared__ float smK[64][100];
    int wl = blockIdx.x >> 3;       // local window
    int wg = w0 + wl;               // global window (for mask region)
    int h = blockIdx.x & 7;
    int t = threadIdx.x;
    const u16* base = QKV + (size_t)wl * NTOK * 2304 + h * HDIM;
    for (int i4 = t; i4 < NTOK * 24; i4 += 256) {
        int nn = i4 / 24, jj = (i4 % 24) * 4;
        const u16* rq = base + (size_t)nn * 2304 + jj;
        ushort4 uq = *(const ushort4*)rq;
        ushort4 uk = *(const ushort4*)(rq + 768);
        float4 fq, fk4;
        fq.x = bf2f(uq.x); fq.y = bf2f(uq.y); fq.z = bf2f(uq.z); fq.w = bf2f(uq.w);
        fk4.x = bf2f(uk.x); fk4.y = bf2f(uk.y); fk4.z = bf2f(uk.z); fk4.w = bf2f(uk.w);
        *(float4*)&smQ[nn][jj] = fq;
        *(float4*)&smK[nn][jj] = fk4;
    }
    __syncthreads();
    if (t < 128) {
        int row = t & 63;
        float4* rp4 = (t < 64) ? (float4*)smQ[row] : (float4*)smK[row];
        float ss = 0.f;
        #pragma unroll
        for (int jj = 0; jj < 24; ++jj) {
            float4 v = rp4[jj];
            ss += v.x * v.x + v.y * v.y + v.z * v.z + v.w * v.w;
        }
        float rn = 1.0f / fmaxf(sqrtf(ss), 1e-12f);
        if (t < 64) rn *= scale[h];
        #pragma unroll
        for (int jj = 0; jj < 24; ++jj) {
            float4 v = rp4[jj];
            v.x *= rn; v.y *= rn; v.z *= rn; v.w *= rn;
            rp4[jj] = v;
        }
    }
    __syncthreads();
    int n = t >> 2, m0q = (t & 3) << 4;
    int p1 = n >> 3, q1 = n & 7;
    int idn = 0, hi = 0, wi = 0;
    if (shift) {
        int wim = wg & 127; hi = wim >> 4; wi = wim & 15;
        idn = reg_r(hi * 8 + p1) * 3 + reg_c(wi * 8 + q1);
    }
    // hoist q row into registers (24 float4 = 96 f)
    float4 qv[24];
    #pragma unroll
    for (int jj = 0; jj < 24; ++jj) qv[jj] = *(const float4*)&smQ[n][jj * 4];
    float P[16];
    #pragma unroll 1
    for (int s = 0; s < 16; ++s) {
        int mm = m0q + s;
        const float4* kr = (const float4*)&smK[mm][0];
        float acc = 0.f;
        #pragma unroll
        for (int jj = 0; jj < 24; ++jj) {
            float4 a = qv[jj], b = kr[jj];
            acc = fmaf(a.x, b.x, acc); acc = fmaf(a.y, b.y, acc);
            acc = fmaf(a.z, b.z, acc); acc = fmaf(a.w, b.w, acc);
        }
        int p2 = mm >> 3, q2 = mm & 7;
        acc += rpb[((p1 - p2 + 7) * 15 + (q1 - q2 + 7)) * NHEADS + h];
        if (shift) {
            int idm = reg_r(hi * 8 + p2) * 3 + reg_c(wi * 8 + q2);
            if (idm != idn) acc -= 100.0f;
        }
        P[s] = acc;
    }
    float mx = P[0];
    #pragma unroll
    for (int s = 1; s < 16; ++s) mx = fmaxf(mx, P[s]);
    mx = fmaxf(mx, __shfl_xor(mx, 1));
    mx = fmaxf(mx, __shfl_xor(mx, 2));
    float sum = 0.f;
    #pragma unroll
    for (int s = 0; s < 16; ++s) { P[s] = __expf(P[s] - mx); sum += P[s]; }
    sum += __shfl_xor(sum, 1);
    sum += __shfl_xor(sum, 2);
    float inv = 1.0f / sum;
    #pragma unroll
    for (int s = 0; s < 16; ++s) P[s] *= inv;
    __syncthreads();   // done reading q
    for (int i4 = t; i4 < NTOK * 24; i4 += 256) {
        int nn = i4 / 24, jj = (i4 % 24) * 4;
        ushort4 uv = *(const ushort4*)(base + (size_t)nn * 2304 + 1536 + jj);
        float4 fv;
        fv.x = bf2f(uv.x); fv.y = bf2f(uv.y); fv.z = bf2f(uv.z); fv.w = bf2f(uv.w);
        *(float4*)&smQ[nn][jj] = fv;   // v
    }
    __syncthreads();
    u16* orow = outw + ((size_t)wl * NTOK + n) * CDIM + h * HDIM;
    #pragma unroll 1
    for (int c0 = 0; c0 < HDIM; c0 += 24) {
        float4 part[6];
        #pragma unroll
        for (int jj = 0; jj < 6; ++jj) { part[jj].x = 0.f; part[jj].y = 0.f; part[jj].z = 0.f; part[jj].w = 0.f; }
        #pragma unroll 1
        for (int s = 0; s < 16; ++s) {
            float pv = P[s];
            const float4* vr = (const float4*)&smQ[m0q + s][c0];
            #pragma unroll
            for (int jj = 0; jj < 6; ++jj) {
                float4 v4 = vr[jj];
                part[jj].x = fmaf(pv, v4.x, part[jj].x);
                part[jj].y = fmaf(pv, v4.y, part[jj].y);
                part[jj].z = fmaf(pv, v4.z, part[jj].z);
                part[jj].w = fmaf(pv, v4.w, part[jj].w);
            }
        }
        #pragma unroll
        for (int jj = 0; jj < 6; ++jj) {
            part[jj].x += __shfl_xor(part[jj].x, 1); part[jj].x += __shfl_xor(part[jj].x, 2);
            part[jj].y += __shfl_xor(part[jj].y, 1); part[jj].y += __shfl_xor(part[jj].y, 2);
            part[jj].z += __shfl_xor(part[jj].z, 1); part[jj].z += __shfl_xor(part[jj].z, 2);
            part[jj].w += __shfl_xor(part[jj].w, 1); part[jj].w += __shfl_xor(part[jj].w, 2);
        }
        if ((t & 3) == (c0 / 24)) {
            u16 tmp[24];
            #pragma unroll
            for (int jj = 0; jj < 6; ++jj) {
                tmp[jj*4+0] = f2bf(part[jj].x); tmp[jj*4+1] = f2bf(part[jj].y);
                tmp[jj*4+2] = f2bf(part[jj].z); tmp[jj*4+3] = f2bf(part[jj].w);
            }
            *(uint4*)&orow[c0]      = *(const uint4*)&tmp[0];
            *(uint4*)&orow[c0 + 8]  = *(const uint4*)&tmp[8];
            *(uint4*)&orow[c0 + 16] = *(const uint4*)&tmp[16];
        }
    }
}

// ---------------- chunked LayerNorm + residual: X[target] += LN(Yc[lm])*g + b ----------------
__global__ __launch_bounds__(256) void k_ln_add(float* __restrict__ X,
                                                const u16* __restrict__ Yc,
                                                const float* __restrict__ g,
                                                const float* __restrict__ bb,
                                                int m0, int shift, int winmap) {
    int lm = blockIdx.x;
    int gm = m0 + lm;
    int target;
    if (winmap) {
        int w = gm >> 6, n = gm & 63;
        int b = w >> 7, wim = w & 127, hi = wim >> 4, wi = wim & 15;
        int p = n >> 3, q = n & 7;
        int r  = (hi * 8 + p + shift) & (HRES - 1);
        int cc = (wi * 8 + q + shift) & (WRES - 1);
        target = (b * HRES + r) * WRES + cc;
    } else {
        target = gm;
    }
    size_t xo = (size_t)target * CDIM;
    size_t yo = (size_t)lm * CDIM;
    int t = threadIdx.x;
    float v0 = bf2f(Yc[yo + t]), v1 = bf2f(Yc[yo + t + 256]), v2 = bf2f(Yc[yo + t + 512]);
    float s = v0 + v1 + v2;
    float ss = v0*v0 + v1*v1 + v2*v2;
    #pragma unroll
    for (int o = 32; o > 0; o >>= 1) {
        s  += __shfl_down(s, o);
        ss += __shfl_down(ss, o);
    }
    __shared__ float rs_[4], rss_[4];
    if ((t & 63) == 0) { rs_[t >> 6] = s; rss_[t >> 6] = ss; }
    __syncthreads();
    float S  = rs_[0] + rs_[1] + rs_[2] + rs_[3];
    float SS = rss_[0] + rss_[1] + rss_[2] + rss_[3];
    float mu = S * (1.0f / CDIM);
    float var = SS * (1.0f / CDIM) - mu * mu;
    float rstd = rsqrtf(fmaxf(var, 0.0f) + 1e-5f);
    X[xo + t]       += (v0 - mu) * rstd * g[t]       + bb[t];
    X[xo + t + 256] += (v1 - mu) * rstd * g[t + 256] + bb[t + 256];
    X[xo + t + 512] += (v2 - mu) * rstd * g[t + 512] + bb[t + 512];
}

// ---------------- host launcher ----------------
extern "C" void kernel_launch(void* const* d_in, const int* in_sizes, int n_in,
                              void* d_out, int out_size, void* d_ws, size_t ws_size,
                              hipStream_t stream) {
    (void)in_sizes; (void)n_in; (void)out_size;
    const float* x_in  = (const float*)d_in[0];
    const float* n1g   = (const float*)d_in[1];
    const float* n1b   = (const float*)d_in[2];
    const float* n2g   = (const float*)d_in[3];
    const float* n2b   = (const float*)d_in[4];
    const float* qkvw  = (const float*)d_in[5];
    const float* qbias = (const float*)d_in[6];
    const float* vbias = (const float*)d_in[7];
    const float* lscal = (const float*)d_in[8];
    const float* cpbw1 = (const float*)d_in[9];
    const float* cpbb1 = (const float*)d_in[10];
    const float* cpbw2 = (const float*)d_in[11];
    const float* projw = (const float*)d_in[12];
    const float* projb = (const float*)d_in[13];
    const float* fc1w  = (const float*)d_in[14];
    const float* fc1b  = (const float*)d_in[15];
    const float* fc2w  = (const float*)d_in[16];
    const float* fc2b  = (const float*)d_in[17];

    // residual stream X lives in d_out (fp32, MTOT*CDIM elements)
    float* X = (float*)d_out;

    // ---- ws layout: header 32 KB | bf16 weights (per depth) | chunk scratch ----
    float* RPB  = (float*)d_ws;                    // 1800 floats
    float* SCAL = RPB + 1800;                      // 8 floats
    float* QKVB = RPB + 1808;                      // 2304 floats (combined qkv bias)
    u16* Wq = (u16*)((char*)d_ws + 32768);         // 2304*768
    u16* Wp = Wq + 2304 * 768;                     // 768*768
    u16* W1 = Wp + 768 * 768;                      // 6144*768
    u16* W2 = W1 + 6144 * 768;                     // 768*3072
    u16* SCR = W2 + 768 * 3072;                    // chunk scratch

    // per-row scratch (uniform for both phases): 4608 u16 = 9216 B
    //  MLP : Xb(768) | Hg(3072) | Yc(768)
    //  attn: Xw(768) | QKV(2304)+OUTW(768) in Hg region | Yc(768)
    long long avail = (long long)ws_size - 32768 - 18874368;
    if (avail < 0) avail = 0;
    long long mc_ll = (avail / 9216) & ~127LL;
    int Mc = (int)(mc_ll < 128 ? 128 : (mc_ll > MTOT ? MTOT : mc_ll));

    u16* Xb   = SCR;                               // Mc*768
    u16* Hg   = Xb + (size_t)Mc * 768;             // Mc*3072
    u16* Yc   = Hg + (size_t)Mc * 3072;            // Mc*768
    u16* QKV  = Hg;                                // alias: Mc*2304
    u16* OUTW = Hg + (size_t)Mc * 2304;            // alias: Mc*768

    // copy input -> residual (fp32, 16B vectors)
    k_copy<<<(MTOT * CDIM) / 1024, 256, 0, stream>>>((const float4*)x_in, (float4*)X);

    for (int d = 0; d < 2; ++d) {
        int shift = d ? 4 : 0;
        // per-depth weight conversion to bf16 (tiny vs GEMM time)
        k_cvt<<<(2304*768/4 + 255)/256, 256, 0, stream>>>(
            (const float4*)(qkvw + (size_t)d * 2304 * 768), (ushort4*)Wq, 2304*768/4);
        k_cvt<<<(768*768/4 + 255)/256, 256, 0, stream>>>(
            (const float4*)(projw + (size_t)d * 768 * 768), (ushort4*)Wp, 768*768/4);
        k_cvt<<<(6144*768/4 + 255)/256, 256, 0, stream>>>(
            (const float4*)(fc1w + (size_t)d * 6144 * 768), (ushort4*)W1, 6144*768/4);
        k_cvt<<<(768*3072/4 + 255)/256, 256, 0, stream>>>(
            (const float4*)(fc2w + (size_t)d * 768 * 3072), (ushort4*)W2, 768*3072/4);
        k_qkvb<<<9, 256, 0, stream>>>(qbias + d * 768, vbias + d * 768, QKVB);
        k_cpb<<<1, 256, 0, stream>>>(cpbw1 + d * 1024, cpbb1 + d * 512,
                                     cpbw2 + d * 4096, lscal + d * 8, RPB, SCAL);
        // ---- attention branch, chunked (chunks touch disjoint X rows) ----
        for (int m0 = 0; m0 < MTOT; m0 += Mc) {
            int cur = (MTOT - m0) < Mc ? (MTOT - m0) : Mc;
            k_xcvt<<<cur, 192, 0, stream>>>(X, Xb, m0, shift, 1);
            k_mm<0><<<dim3(cur / 128, 2304 / 128), 256, 0, stream>>>(
                Xb, Wq, QKVB, QKV, 768, 2304);
            k_attn<<<(cur / 64) * NHEADS, 256, 0, stream>>>(QKV, RPB, SCAL, OUTW,
                                                            shift, m0 / 64);
            k_mm<0><<<dim3(cur / 128, 768 / 128), 256, 0, stream>>>(
                OUTW, Wp, projb + d * 768, Yc, 768, 768);
            k_ln_add<<<cur, 256, 0, stream>>>(X, Yc, n1g + d * 768, n1b + d * 768,
                                              m0, shift, 1);
        }
        // ---- MLP branch, chunked ----
        for (int m0 = 0; m0 < MTOT; m0 += Mc) {
            int cur = (MTOT - m0) < Mc ? (MTOT - m0) : Mc;
            k_xcvt<<<cur, 192, 0, stream>>>(X, Xb, m0, 0, 0);
            // gate half: Hg = gelu(X@Wg^T + bg)
            k_mm<1><<<dim3(cur / 128, 3072 / 128), 256, 0, stream>>>(
                Xb, W1, fc1b + d * 6144, Hg, 768, 3072);
            // val half: Hg *= (X@Wv^T + bv)
            k_mm<2><<<dim3(cur / 128, 3072 / 128), 256, 0, stream>>>(
                Xb, W1 + (size_t)3072 * 768, fc1b + d * 6144 + 3072, Hg, 768, 3072);
            k_mm<0><<<dim3(cur / 128, 768 / 128), 256, 0, stream>>>(
                Hg, W2, fc2b + d * 768, Yc, 3072, 768);
            k_ln_add<<<cur, 256, 0, stream>>>(X, Yc, n2g + d * 768, n2b + d * 768,
                                              m0, 0, 0);
        }
    }
}

// Round 2
// 4507.351 us; speedup vs baseline: 4.1242x; 1.0151x over previous
//
#include <hip/hip_runtime.h>
#include <hip/hip_bf16.h>
#include <math.h>

// ---------------- problem constants ----------------
#define HRES   64
#define WRES   128
#define CDIM   768
#define NHEADS 8
#define WINSZ  8
#define NTOK   64          // WINSZ*WINSZ
#define HDIM   96          // CDIM/NHEADS
#define HIDDIM 3072
#define NWH    8           // HRES/WINSZ
#define NWW    16          // WRES/WINSZ
#define NWIMG  128         // NWH*NWW
#define NWTOT  512         // B*NWIMG
#define MTOT   32768       // NWTOT*NTOK
#define CPBH   512

typedef unsigned short u16;
typedef __attribute__((ext_vector_type(8))) short bf16x8;   // 8 bf16 in 4 VGPRs
typedef __attribute__((ext_vector_type(4))) float f32x4;

__device__ __forceinline__ float bf2f(u16 u) {
    return __uint_as_float(((unsigned)u) << 16);
}
__device__ __forceinline__ u16 f2bf(float f) {
    unsigned u = __float_as_uint(f);
    u += 0x7FFFu + ((u >> 16) & 1u);
    return (u16)(u >> 16);
}
__device__ __forceinline__ float gelu_exact(float x) {
    return 0.5f * x * (1.0f + erff(x * 0.70710678118654752f));
}
__device__ __forceinline__ int reg_r(int r) { return r < HRES-8 ? 0 : (r < HRES-4 ? 1 : 2); }
__device__ __forceinline__ int reg_c(int c) { return c < WRES-8 ? 0 : (c < WRES-4 ? 1 : 2); }

// async global -> LDS, 16 bytes per lane; lds base must be wave-uniform
__device__ __forceinline__ void glds16(const u16* g, u16* l) {
    __builtin_amdgcn_global_load_lds(
        (const __attribute__((address_space(1))) void*)g,
        (__attribute__((address_space(3))) void*)l, 16, 0, 0);
}

// ---------------- fp32 copy input -> residual X (in d_out) ----------------
__global__ __launch_bounds__(256) void k_copy(const float4* __restrict__ in,
                                              float4* __restrict__ out) {
    size_t i = (size_t)blockIdx.x * 256 + threadIdx.x;
    out[i] = in[i];
}

// ---------------- generic fp32 -> bf16 conversion (weights) ----------------
__global__ __launch_bounds__(256) void k_cvt(const float4* __restrict__ in,
                                             ushort4* __restrict__ out, int n4) {
    int i = blockIdx.x * 256 + threadIdx.x;
    if (i < n4) {
        float4 v = in[i];
        ushort4 o;
        o.x = f2bf(v.x); o.y = f2bf(v.y); o.z = f2bf(v.z); o.w = f2bf(v.w);
        out[i] = o;
    }
}

// ---------------- build combined qkv bias (q | 0 | v), fp32 ----------------
__global__ __launch_bounds__(256) void k_qkvb(const float* __restrict__ qb,
                                              const float* __restrict__ vb,
                                              float* __restrict__ dst) {
    int i = blockIdx.x * 256 + threadIdx.x;
    if (i < 2304)
        dst[i] = (i < 768) ? qb[i] : ((i < 1536) ? 0.f : vb[i - 1536]);
}

// ---------------- X rows -> bf16 rows, optional shifted-window gather ----------------
__global__ __launch_bounds__(192) void k_xcvt(const float* __restrict__ X,
                                              u16* __restrict__ out,
                                              int m0, int shift, int winmap) {
    int lm = blockIdx.x, t = threadIdx.x;
    int gm = m0 + lm;
    int src;
    if (winmap) {
        int w = gm >> 6, n = gm & 63;
        int b = w >> 7, wim = w & 127, hi = wim >> 4, wi = wim & 15;
        int p = n >> 3, q = n & 7;
        int r  = (hi * 8 + p + shift) & (HRES - 1);
        int cc = (wi * 8 + q + shift) & (WRES - 1);
        src = (b * HRES + r) * WRES + cc;
    } else {
        src = gm;
    }
    float4 v = *(const float4*)(X + (size_t)src * CDIM + t * 4);
    ushort4 o;
    o.x = f2bf(v.x); o.y = f2bf(v.y); o.z = f2bf(v.z); o.w = f2bf(v.w);
    *(ushort4*)(out + (size_t)lm * CDIM + t * 4) = o;
}

// ---------------- CPB MLP: rpb table (225 x 8) + per-head scale ----------------
__global__ __launch_bounds__(256) void k_cpb(const float* __restrict__ w1,
                                             const float* __restrict__ b1,
                                             const float* __restrict__ w2,
                                             const float* __restrict__ ls,
                                             float* __restrict__ rpb,
                                             float* __restrict__ scale) {
    int t = threadIdx.x;
    if (t < NHEADS) scale[t] = __expf(fminf(ls[t], 4.6051701859880914f)); // ln(100)
    for (int idx = t; idx < 225 * NHEADS; idx += 256) {
        int tt = idx >> 3, h = idx & 7;
        int i = tt / 15, j = tt % 15;
        float vi = 8.0f * (float)(i - 7) / 7.0f;
        float vj = 8.0f * (float)(j - 7) / 7.0f;
        float si = (vi > 0.f) ? 1.f : ((vi < 0.f) ? -1.f : 0.f);
        float sj = (vj > 0.f) ? 1.f : ((vj < 0.f) ? -1.f : 0.f);
        float c0 = si * log2f(fabsf(vi) + 1.0f) * (1.0f / 3.0f);
        float c1 = sj * log2f(fabsf(vj) + 1.0f) * (1.0f / 3.0f);
        float sum = 0.f;
        for (int k = 0; k < CPBH; ++k) {
            float hv = c0 * w1[2*k] + c1 * w1[2*k+1] + b1[k];
            if (hv > 0.f) sum += hv * w2[h * CPBH + k];
        }
        rpb[idx] = 16.0f / (1.0f + __expf(-sum));
    }
}

// ---------------- bf16 MFMA GEMM: C[M][N] = A[M][K] @ Bw[N][K]^T + bias ----------------
// 128x128 tile, 4 waves (64x64 quadrant each), mfma_f32_16x16x32_bf16.
// global_load_lds width-16 staging, LDS double-buffer, 1 barrier per K-step.
// grid: x = N-tiles (few, share A-tile), y = M-tiles.
__global__ __launch_bounds__(256) void k_mm(const u16* __restrict__ A,
                                            const u16* __restrict__ Bw,
                                            const float* __restrict__ bias,
                                            u16* __restrict__ C,
                                            int K, int N) {
    __shared__ __align__(16) u16 As[2][4096];   // [128][32] bf16 per buffer
    __shared__ __align__(16) u16 Bs[2][4096];
    int t = threadIdx.x;
    int tn = blockIdx.x << 7, tm = blockIdx.y << 7;
    int l = t & 63, wv = t >> 6;
    // staging coords: wave wv covers rows [wv*32, wv*32+32), 2 issues of 16 rows
    int sr = l >> 2;            // 0..15 (row within issue)
    int sc = (l & 3) << 3;      // bf16 col 0,8,16,24
    const u16* Ag0 = A  + (size_t)(tm + wv * 32 + sr) * K + sc;
    const u16* Ag1 = Ag0 + (size_t)16 * K;
    const u16* Bg0 = Bw + (size_t)(tn + wv * 32 + sr) * K + sc;
    const u16* Bg1 = Bg0 + (size_t)16 * K;
    int wb = wv * 1024;         // wave's LDS slice (u16 units)
    // fragment coords
    int fr = l & 15, fk = l >> 4;
    int r0 = (wv >> 1) << 6, c0 = (wv & 1) << 6;
    f32x4 acc[4][4];
    #pragma unroll
    for (int i = 0; i < 4; ++i)
        #pragma unroll
        for (int j = 0; j < 4; ++j)
            acc[i][j] = (f32x4){0.f, 0.f, 0.f, 0.f};

    #define STAGE_MM(buf, kof) do { \
        glds16(Ag0 + (kof), &As[buf][wb]); \
        glds16(Ag1 + (kof), &As[buf][wb + 512]); \
        glds16(Bg0 + (kof), &Bs[buf][wb]); \
        glds16(Bg1 + (kof), &Bs[buf][wb + 512]); \
    } while (0)

    STAGE_MM(0, 0);
    __syncthreads();
    int nk = K >> 5;
    for (int ks = 0; ks < nk; ++ks) {
        int cur = ks & 1;
        if (ks + 1 < nk) STAGE_MM(cur ^ 1, (ks + 1) << 5);
        bf16x8 Af[4], Bf[4];
        #pragma unroll
        for (int i = 0; i < 4; ++i)
            Af[i] = *(const bf16x8*)&As[cur][((r0 + i * 16 + fr) << 5) + (fk << 3)];
        #pragma unroll
        for (int j = 0; j < 4; ++j)
            Bf[j] = *(const bf16x8*)&Bs[cur][((c0 + j * 16 + fr) << 5) + (fk << 3)];
        #pragma unroll
        for (int i = 0; i < 4; ++i)
            #pragma unroll
            for (int j = 0; j < 4; ++j)
                acc[i][j] = __builtin_amdgcn_mfma_f32_16x16x32_bf16(Af[i], Bf[j], acc[i][j], 0, 0, 0);
        __syncthreads();   // waves done reading cur; next-stage vmcnt drained
    }
    #undef STAGE_MM
    // epilogue: C/D layout col = lane&15, row = (lane>>4)*4 + reg  [verified m89]
    int lr4 = fk << 2;
    #pragma unroll
    for (int j = 0; j < 4; ++j) {
        int col = tn + c0 + j * 16 + fr;
        float bj = bias[col];
        #pragma unroll
        for (int i = 0; i < 4; ++i) {
            int row = tm + r0 + i * 16 + lr4;
            #pragma unroll
            for (int r = 0; r < 4; ++r)
                C[(size_t)(row + r) * N + col] = f2bf(acc[i][j][r] + bj);
        }
    }
}

// ---------------- fused gated fc1: Hg = gelu(X@Wg^T+bg) * (X@Wv^T+bv) ----------------
// same structure; stages A + gate-B + val-B tiles, 32 MFMA per K-step.
__global__ __launch_bounds__(256) void k_mm_fc1(const u16* __restrict__ A,
                                                const u16* __restrict__ Bw,
                                                const float* __restrict__ fb,
                                                u16* __restrict__ C,
                                                int K) {
    __shared__ __align__(16) u16 As[2][4096];
    __shared__ __align__(16) u16 Gs[2][4096];
    __shared__ __align__(16) u16 Vs[2][4096];
    int t = threadIdx.x;
    int tn = blockIdx.x << 7, tm = blockIdx.y << 7;
    int l = t & 63, wv = t >> 6;
    int sr = l >> 2;
    int sc = (l & 3) << 3;
    const u16* Ag0 = A  + (size_t)(tm + wv * 32 + sr) * K + sc;
    const u16* Ag1 = Ag0 + (size_t)16 * K;
    const u16* Gg0 = Bw + (size_t)(tn + wv * 32 + sr) * K + sc;
    const u16* Gg1 = Gg0 + (size_t)16 * K;
    const u16* Vg0 = Gg0 + (size_t)HIDDIM * K;
    const u16* Vg1 = Gg1 + (size_t)HIDDIM * K;
    int wb = wv * 1024;
    int fr = l & 15, fk = l >> 4;
    int r0 = (wv >> 1) << 6, c0 = (wv & 1) << 6;
    f32x4 accg[4][4], accv[4][4];
    #pragma unroll
    for (int i = 0; i < 4; ++i)
        #pragma unroll
        for (int j = 0; j < 4; ++j) {
            accg[i][j] = (f32x4){0.f, 0.f, 0.f, 0.f};
            accv[i][j] = (f32x4){0.f, 0.f, 0.f, 0.f};
        }

    #define STAGE_FC1(buf, kof) do { \
        glds16(Ag0 + (kof), &As[buf][wb]); \
        glds16(Ag1 + (kof), &As[buf][wb + 512]); \
        glds16(Gg0 + (kof), &Gs[buf][wb]); \
        glds16(Gg1 + (kof), &Gs[buf][wb + 512]); \
        glds16(Vg0 + (kof), &Vs[buf][wb]); \
        glds16(Vg1 + (kof), &Vs[buf][wb + 512]); \
    } while (0)

    STAGE_FC1(0, 0);
    __syncthreads();
    int nk = K >> 5;
    for (int ks = 0; ks < nk; ++ks) {
        int cur = ks & 1;
        if (ks + 1 < nk) STAGE_FC1(cur ^ 1, (ks + 1) << 5);
        bf16x8 Af[4], Gf[4], Vf[4];
        #pragma unroll
        for (int i = 0; i < 4; ++i)
            Af[i] = *(const bf16x8*)&As[cur][((r0 + i * 16 + fr) << 5) + (fk << 3)];
        #pragma unroll
        for (int j = 0; j < 4; ++j) {
            int o = ((c0 + j * 16 + fr) << 5) + (fk << 3);
            Gf[j] = *(const bf16x8*)&Gs[cur][o];
            Vf[j] = *(const bf16x8*)&Vs[cur][o];
        }
        #pragma unroll
        for (int i = 0; i < 4; ++i)
            #pragma unroll
            for (int j = 0; j < 4; ++j) {
                accg[i][j] = __builtin_amdgcn_mfma_f32_16x16x32_bf16(Af[i], Gf[j], accg[i][j], 0, 0, 0);
                accv[i][j] = __builtin_amdgcn_mfma_f32_16x16x32_bf16(Af[i], Vf[j], accv[i][j], 0, 0, 0);
            }
        __syncthreads();
    }
    #undef STAGE_FC1
    int lr4 = fk << 2;
    #pragma unroll
    for (int j = 0; j < 4; ++j) {
        int col = tn + c0 + j * 16 + fr;
        float bg_ = fb[col];
        float bv_ = fb[col + HIDDIM];
        #pragma unroll
        for (int i = 0; i < 4; ++i) {
            int row = tm + r0 + i * 16 + lr4;
            #pragma unroll
            for (int r = 0; r < 4; ++r) {
                float g = accg[i][j][r] + bg_;
                float v = accv[i][j][r] + bv_;
                C[(size_t)(row + r) * HIDDIM + col] = f2bf(gelu_exact(g) * v);
            }
        }
    }
}

// ---------------- fused attention per (window, head); bf16 in/out ----------------
__global__ __launch_bounds__(256) void k_attn(const u16* __restrict__ QKV,
                                              const float* __restrict__ rpb,
                                              const float* __restrict__ scale,
                                              u16* __restrict__ outw,
                                              int shift, int w0) {
    __shared__ float smQ[64][100];   // q, later reused for v (pad 100: float4-aligned rows)
    __shared__ float smK[64][100];
    int wl = blockIdx.x >> 3;       // local window
    int wg = w0 + wl;               // global window (for mask region)
    int h = blockIdx.x & 7;
    int t = threadIdx.x;
    const u16* base = QKV + (size_t)wl * NTOK * 2304 + h * HDIM;
    for (int i4 = t; i4 < NTOK * 24; i4 += 256) {
        int nn = i4 / 24, jj = (i4 % 24) * 4;
        const u16* rq = base + (size_t)nn * 2304 + jj;
        ushort4 uq = *(const ushort4*)rq;
        ushort4 uk = *(const ushort4*)(rq + 768);
        float4 fq, fk4;
        fq.x = bf2f(uq.x); fq.y = bf2f(uq.y); fq.z = bf2f(uq.z); fq.w = bf2f(uq.w);
        fk4.x = bf2f(uk.x); fk4.y = bf2f(uk.y); fk4.z = bf2f(uk.z); fk4.w = bf2f(uk.w);
        *(float4*)&smQ[nn][jj] = fq;
        *(float4*)&smK[nn][jj] = fk4;
    }
    __syncthreads();
    if (t < 128) {
        int row = t & 63;
        float4* rp4 = (t < 64) ? (float4*)smQ[row] : (float4*)smK[row];
        float ss = 0.f;
        #pragma unroll
        for (int jj = 0; jj < 24; ++jj) {
            float4 v = rp4[jj];
            ss += v.x * v.x + v.y * v.y + v.z * v.z + v.w * v.w;
        }
        float rn = 1.0f / fmaxf(sqrtf(ss), 1e-12f);
        if (t < 64) rn *= scale[h];
        #pragma unroll
        for (int jj = 0; jj < 24; ++jj) {
            float4 v = rp4[jj];
            v.x *= rn; v.y *= rn; v.z *= rn; v.w *= rn;
            rp4[jj] = v;
        }
    }
    __syncthreads();
    int n = t >> 2, m0q = (t & 3) << 4;
    int p1 = n >> 3, q1 = n & 7;
    int idn = 0, hi = 0, wi = 0;
    if (shift) {
        int wim = wg & 127; hi = wim >> 4; wi = wim & 15;
        idn = reg_r(hi * 8 + p1) * 3 + reg_c(wi * 8 + q1);
    }
    float4 qv[24];
    #pragma unroll
    for (int jj = 0; jj < 24; ++jj) qv[jj] = *(const float4*)&smQ[n][jj * 4];
    float P[16];
    #pragma unroll 1
    for (int s = 0; s < 16; ++s) {
        int mm = m0q + s;
        const float4* kr = (const float4*)&smK[mm][0];
        float acc = 0.f;
        #pragma unroll
        for (int jj = 0; jj < 24; ++jj) {
            float4 a = qv[jj], b = kr[jj];
            acc = fmaf(a.x, b.x, acc); acc = fmaf(a.y, b.y, acc);
            acc = fmaf(a.z, b.z, acc); acc = fmaf(a.w, b.w, acc);
        }
        int p2 = mm >> 3, q2 = mm & 7;
        acc += rpb[((p1 - p2 + 7) * 15 + (q1 - q2 + 7)) * NHEADS + h];
        if (shift) {
            int idm = reg_r(hi * 8 + p2) * 3 + reg_c(wi * 8 + q2);
            if (idm != idn) acc -= 100.0f;
        }
        P[s] = acc;
    }
    float mx = P[0];
    #pragma unroll
    for (int s = 1; s < 16; ++s) mx = fmaxf(mx, P[s]);
    mx = fmaxf(mx, __shfl_xor(mx, 1));
    mx = fmaxf(mx, __shfl_xor(mx, 2));
    float sum = 0.f;
    #pragma unroll
    for (int s = 0; s < 16; ++s) { P[s] = __expf(P[s] - mx); sum += P[s]; }
    sum += __shfl_xor(sum, 1);
    sum += __shfl_xor(sum, 2);
    float inv = 1.0f / sum;
    #pragma unroll
    for (int s = 0; s < 16; ++s) P[s] *= inv;
    __syncthreads();   // done reading q
    for (int i4 = t; i4 < NTOK * 24; i4 += 256) {
        int nn = i4 / 24, jj = (i4 % 24) * 4;
        ushort4 uv = *(const ushort4*)(base + (size_t)nn * 2304 + 1536 + jj);
        float4 fv;
        fv.x = bf2f(uv.x); fv.y = bf2f(uv.y); fv.z = bf2f(uv.z); fv.w = bf2f(uv.w);
        *(float4*)&smQ[nn][jj] = fv;   // v
    }
    __syncthreads();
    u16* orow = outw + ((size_t)wl * NTOK + n) * CDIM + h * HDIM;
    #pragma unroll 1
    for (int c0 = 0; c0 < HDIM; c0 += 24) {
        float4 part[6];
        #pragma unroll
        for (int jj = 0; jj < 6; ++jj) { part[jj].x = 0.f; part[jj].y = 0.f; part[jj].z = 0.f; part[jj].w = 0.f; }
        #pragma unroll 1
        for (int s = 0; s < 16; ++s) {
            float pv = P[s];
            const float4* vr = (const float4*)&smQ[m0q + s][c0];
            #pragma unroll
            for (int jj = 0; jj < 6; ++jj) {
                float4 v4 = vr[jj];
                part[jj].x = fmaf(pv, v4.x, part[jj].x);
                part[jj].y = fmaf(pv, v4.y, part[jj].y);
                part[jj].z = fmaf(pv, v4.z, part[jj].z);
                part[jj].w = fmaf(pv, v4.w, part[jj].w);
            }
        }
        #pragma unroll
        for (int jj = 0; jj < 6; ++jj) {
            part[jj].x += __shfl_xor(part[jj].x, 1); part[jj].x += __shfl_xor(part[jj].x, 2);
            part[jj].y += __shfl_xor(part[jj].y, 1); part[jj].y += __shfl_xor(part[jj].y, 2);
            part[jj].z += __shfl_xor(part[jj].z, 1); part[jj].z += __shfl_xor(part[jj].z, 2);
            part[jj].w += __shfl_xor(part[jj].w, 1); part[jj].w += __shfl_xor(part[jj].w, 2);
        }
        if ((t & 3) == (c0 / 24)) {
            u16 tmp[24];
            #pragma unroll
            for (int jj = 0; jj < 6; ++jj) {
                tmp[jj*4+0] = f2bf(part[jj].x); tmp[jj*4+1] = f2bf(part[jj].y);
                tmp[jj*4+2] = f2bf(part[jj].z); tmp[jj*4+3] = f2bf(part[jj].w);
            }
            *(uint4*)&orow[c0]      = *(const uint4*)&tmp[0];
            *(uint4*)&orow[c0 + 8]  = *(const uint4*)&tmp[8];
            *(uint4*)&orow[c0 + 16] = *(const uint4*)&tmp[16];
        }
    }
}

// ---------------- chunked LayerNorm + residual: X[target] += LN(Yc[lm])*g + b ----------------
__global__ __launch_bounds__(256) void k_ln_add(float* __restrict__ X,
                                                const u16* __restrict__ Yc,
                                                const float* __restrict__ g,
                                                const float* __restrict__ bb,
                                                int m0, int shift, int winmap) {
    int lm = blockIdx.x;
    int gm = m0 + lm;
    int target;
    if (winmap) {
        int w = gm >> 6, n = gm & 63;
        int b = w >> 7, wim = w & 127, hi = wim >> 4, wi = wim & 15;
        int p = n >> 3, q = n & 7;
        int r  = (hi * 8 + p + shift) & (HRES - 1);
        int cc = (wi * 8 + q + shift) & (WRES - 1);
        target = (b * HRES + r) * WRES + cc;
    } else {
        target = gm;
    }
    size_t xo = (size_t)target * CDIM;
    size_t yo = (size_t)lm * CDIM;
    int t = threadIdx.x;
    float v0 = bf2f(Yc[yo + t]), v1 = bf2f(Yc[yo + t + 256]), v2 = bf2f(Yc[yo + t + 512]);
    float s = v0 + v1 + v2;
    float ss = v0*v0 + v1*v1 + v2*v2;
    #pragma unroll
    for (int o = 32; o > 0; o >>= 1) {
        s  += __shfl_down(s, o);
        ss += __shfl_down(ss, o);
    }
    __shared__ float rs_[4], rss_[4];
    if ((t & 63) == 0) { rs_[t >> 6] = s; rss_[t >> 6] = ss; }
    __syncthreads();
    float S  = rs_[0] + rs_[1] + rs_[2] + rs_[3];
    float SS = rss_[0] + rss_[1] + rss_[2] + rss_[3];
    float mu = S * (1.0f / CDIM);
    float var = SS * (1.0f / CDIM) - mu * mu;
    float rstd = rsqrtf(fmaxf(var, 0.0f) + 1e-5f);
    X[xo + t]       += (v0 - mu) * rstd * g[t]       + bb[t];
    X[xo + t + 256] += (v1 - mu) * rstd * g[t + 256] + bb[t + 256];
    X[xo + t + 512] += (v2 - mu) * rstd * g[t + 512] + bb[t + 512];
}

// ---------------- host launcher ----------------
extern "C" void kernel_launch(void* const* d_in, const int* in_sizes, int n_in,
                              void* d_out, int out_size, void* d_ws, size_t ws_size,
                              hipStream_t stream) {
    (void)in_sizes; (void)n_in; (void)out_size;
    const float* x_in  = (const float*)d_in[0];
    const float* n1g   = (const float*)d_in[1];
    const float* n1b   = (const float*)d_in[2];
    const float* n2g   = (const float*)d_in[3];
    const float* n2b   = (const float*)d_in[4];
    const float* qkvw  = (const float*)d_in[5];
    const float* qbias = (const float*)d_in[6];
    const float* vbias = (const float*)d_in[7];
    const float* lscal = (const float*)d_in[8];
    const float* cpbw1 = (const float*)d_in[9];
    const float* cpbb1 = (const float*)d_in[10];
    const float* cpbw2 = (const float*)d_in[11];
    const float* projw = (const float*)d_in[12];
    const float* projb = (const float*)d_in[13];
    const float* fc1w  = (const float*)d_in[14];
    const float* fc1b  = (const float*)d_in[15];
    const float* fc2w  = (const float*)d_in[16];
    const float* fc2b  = (const float*)d_in[17];

    // residual stream X lives in d_out (fp32, MTOT*CDIM elements)
    float* X = (float*)d_out;

    // ---- ws layout: header 32 KB | bf16 weights (per depth) | chunk scratch ----
    float* RPB  = (float*)d_ws;                    // 1800 floats
    float* SCAL = RPB + 1800;                      // 8 floats
    float* QKVB = RPB + 1808;                      // 2304 floats (combined qkv bias)
    u16* Wq = (u16*)((char*)d_ws + 32768);         // 2304*768
    u16* Wp = Wq + 2304 * 768;                     // 768*768
    u16* W1 = Wp + 768 * 768;                      // 6144*768
    u16* W2 = W1 + 6144 * 768;                     // 768*3072
    u16* SCR = W2 + 768 * 3072;                    // chunk scratch

    // per-row scratch (uniform for both phases): 4608 u16 = 9216 B
    //  MLP : Xb(768) | Hg(3072) | Yc(768)
    //  attn: Xw(768) | QKV(2304)+OUTW(768) in Hg region | Yc(768)
    long long avail = (long long)ws_size - 32768 - 18874368;
    if (avail < 0) avail = 0;
    long long mc_ll = (avail / 9216) & ~127LL;
    int Mc = (int)(mc_ll < 128 ? 128 : (mc_ll > MTOT ? MTOT : mc_ll));

    u16* Xb   = SCR;                               // Mc*768
    u16* Hg   = Xb + (size_t)Mc * 768;             // Mc*3072
    u16* Yc   = Hg + (size_t)Mc * 3072;            // Mc*768
    u16* QKV  = Hg;                                // alias: Mc*2304
    u16* OUTW = Hg + (size_t)Mc * 2304;            // alias: Mc*768

    // copy input -> residual (fp32, 16B vectors)
    k_copy<<<(MTOT * CDIM) / 1024, 256, 0, stream>>>((const float4*)x_in, (float4*)X);

    for (int d = 0; d < 2; ++d) {
        int shift = d ? 4 : 0;
        // per-depth weight conversion to bf16 (tiny vs GEMM time)
        k_cvt<<<(2304*768/4 + 255)/256, 256, 0, stream>>>(
            (const float4*)(qkvw + (size_t)d * 2304 * 768), (ushort4*)Wq, 2304*768/4);
        k_cvt<<<(768*768/4 + 255)/256, 256, 0, stream>>>(
            (const float4*)(projw + (size_t)d * 768 * 768), (ushort4*)Wp, 768*768/4);
        k_cvt<<<(6144*768/4 + 255)/256, 256, 0, stream>>>(
            (const float4*)(fc1w + (size_t)d * 6144 * 768), (ushort4*)W1, 6144*768/4);
        k_cvt<<<(768*3072/4 + 255)/256, 256, 0, stream>>>(
            (const float4*)(fc2w + (size_t)d * 768 * 3072), (ushort4*)W2, 768*3072/4);
        k_qkvb<<<9, 256, 0, stream>>>(qbias + d * 768, vbias + d * 768, QKVB);
        k_cpb<<<1, 256, 0, stream>>>(cpbw1 + d * 1024, cpbb1 + d * 512,
                                     cpbw2 + d * 4096, lscal + d * 8, RPB, SCAL);
        // ---- attention branch, chunked (chunks touch disjoint X rows) ----
        for (int m0 = 0; m0 < MTOT; m0 += Mc) {
            int cur = (MTOT - m0) < Mc ? (MTOT - m0) : Mc;
            k_xcvt<<<cur, 192, 0, stream>>>(X, Xb, m0, shift, 1);
            k_mm<<<dim3(2304 / 128, cur / 128), 256, 0, stream>>>(
                Xb, Wq, QKVB, QKV, 768, 2304);
            k_attn<<<(cur / 64) * NHEADS, 256, 0, stream>>>(QKV, RPB, SCAL, OUTW,
                                                            shift, m0 / 64);
            k_mm<<<dim3(768 / 128, cur / 128), 256, 0, stream>>>(
                OUTW, Wp, projb + d * 768, Yc, 768, 768);
            k_ln_add<<<cur, 256, 0, stream>>>(X, Yc, n1g + d * 768, n1b + d * 768,
                                              m0, shift, 1);
        }
        // ---- MLP branch, chunked ----
        for (int m0 = 0; m0 < MTOT; m0 += Mc) {
            int cur = (MTOT - m0) < Mc ? (MTOT - m0) : Mc;
            k_xcvt<<<cur, 192, 0, stream>>>(X, Xb, m0, 0, 0);
            // fused gated fc1: Hg = gelu(X@Wg^T+bg) * (X@Wv^T+bv)
            k_mm_fc1<<<dim3(3072 / 128, cur / 128), 256, 0, stream>>>(
                Xb, W1, fc1b + d * 6144, Hg, 768);
            k_mm<<<dim3(768 / 128, cur / 128), 256, 0, stream>>>(
                Hg, W2, fc2b + d * 768, Yc, 3072, 768);
            k_ln_add<<<cur, 256, 0, stream>>>(X, Yc, n2g + d * 768, n2b + d * 768,
                                              m0, 0, 0);
        }
    }
}

// Round 4
// 4440.454 us; speedup vs baseline: 4.1863x; 1.0151x over previous
//
#include <hip/hip_runtime.h>
#include <hip/hip_bf16.h>
#include <math.h>

// ---------------- problem constants ----------------
#define HRES   64
#define WRES   128
#define CDIM   768
#define NHEADS 8
#define WINSZ  8
#define NTOK   64          // WINSZ*WINSZ
#define HDIM   96          // CDIM/NHEADS
#define HIDDIM 3072
#define NWH    8           // HRES/WINSZ
#define NWW    16          // WRES/WINSZ
#define NWIMG  128         // NWH*NWW
#define NWTOT  512         // B*NWIMG
#define MTOT   32768       // NWTOT*NTOK
#define CPBH   512

typedef unsigned short u16;
typedef __attribute__((ext_vector_type(8))) short bf16x8;   // 8 bf16 in 4 VGPRs
typedef __attribute__((ext_vector_type(4))) float f32x4;

__device__ __forceinline__ float bf2f(u16 u) {
    return __uint_as_float(((unsigned)u) << 16);
}
__device__ __forceinline__ u16 f2bf(float f) {
    unsigned u = __float_as_uint(f);
    u += 0x7FFFu + ((u >> 16) & 1u);
    return (u16)(u >> 16);
}
__device__ __forceinline__ float gelu_exact(float x) {
    return 0.5f * x * (1.0f + erff(x * 0.70710678118654752f));
}
__device__ __forceinline__ int reg_r(int r) { return r < HRES-8 ? 0 : (r < HRES-4 ? 1 : 2); }
__device__ __forceinline__ int reg_c(int c) { return c < WRES-8 ? 0 : (c < WRES-4 ? 1 : 2); }

// async global -> LDS, 16 bytes per lane; lds base must be wave-uniform
__device__ __forceinline__ void glds16(const u16* g, u16* l) {
    __builtin_amdgcn_global_load_lds(
        (const __attribute__((address_space(1))) void*)g,
        (__attribute__((address_space(3))) void*)l, 16, 0, 0);
}

// ---------------- fp32 copy input -> residual X (in d_out) ----------------
__global__ __launch_bounds__(256) void k_copy(const float4* __restrict__ in,
                                              float4* __restrict__ out) {
    size_t i = (size_t)blockIdx.x * 256 + threadIdx.x;
    out[i] = in[i];
}

// ---------------- generic fp32 -> bf16 conversion (weights) ----------------
__global__ __launch_bounds__(256) void k_cvt(const float4* __restrict__ in,
                                             ushort4* __restrict__ out, int n4) {
    int i = blockIdx.x * 256 + threadIdx.x;
    if (i < n4) {
        float4 v = in[i];
        ushort4 o;
        o.x = f2bf(v.x); o.y = f2bf(v.y); o.z = f2bf(v.z); o.w = f2bf(v.w);
        out[i] = o;
    }
}

// ---------------- build combined qkv bias (q | 0 | v), fp32 ----------------
__global__ __launch_bounds__(256) void k_qkvb(const float* __restrict__ qb,
                                              const float* __restrict__ vb,
                                              float* __restrict__ dst) {
    int i = blockIdx.x * 256 + threadIdx.x;
    if (i < 2304)
        dst[i] = (i < 768) ? qb[i] : ((i < 1536) ? 0.f : vb[i - 1536]);
}

// ---------------- X rows -> bf16 rows, optional shifted-window gather ----------------
__global__ __launch_bounds__(192) void k_xcvt(const float* __restrict__ X,
                                              u16* __restrict__ out,
                                              int m0, int shift, int winmap) {
    int lm = blockIdx.x, t = threadIdx.x;
    int gm = m0 + lm;
    int src;
    if (winmap) {
        int w = gm >> 6, n = gm & 63;
        int b = w >> 7, wim = w & 127, hi = wim >> 4, wi = wim & 15;
        int p = n >> 3, q = n & 7;
        int r  = (hi * 8 + p + shift) & (HRES - 1);
        int cc = (wi * 8 + q + shift) & (WRES - 1);
        src = (b * HRES + r) * WRES + cc;
    } else {
        src = gm;
    }
    float4 v = *(const float4*)(X + (size_t)src * CDIM + t * 4);
    ushort4 o;
    o.x = f2bf(v.x); o.y = f2bf(v.y); o.z = f2bf(v.z); o.w = f2bf(v.w);
    *(ushort4*)(out + (size_t)lm * CDIM + t * 4) = o;
}

// ---------------- CPB MLP: rpb table (225 x 8) + per-head scale ----------------
__global__ __launch_bounds__(256) void k_cpb(const float* __restrict__ w1,
                                             const float* __restrict__ b1,
                                             const float* __restrict__ w2,
                                             const float* __restrict__ ls,
                                             float* __restrict__ rpb,
                                             float* __restrict__ scale) {
    int t = threadIdx.x;
    if (t < NHEADS) scale[t] = __expf(fminf(ls[t], 4.6051701859880914f)); // ln(100)
    for (int idx = t; idx < 225 * NHEADS; idx += 256) {
        int tt = idx >> 3, h = idx & 7;
        int i = tt / 15, j = tt % 15;
        float vi = 8.0f * (float)(i - 7) / 7.0f;
        float vj = 8.0f * (float)(j - 7) / 7.0f;
        float si = (vi > 0.f) ? 1.f : ((vi < 0.f) ? -1.f : 0.f);
        float sj = (vj > 0.f) ? 1.f : ((vj < 0.f) ? -1.f : 0.f);
        float c0 = si * log2f(fabsf(vi) + 1.0f) * (1.0f / 3.0f);
        float c1 = sj * log2f(fabsf(vj) + 1.0f) * (1.0f / 3.0f);
        float sum = 0.f;
        for (int k = 0; k < CPBH; ++k) {
            float hv = c0 * w1[2*k] + c1 * w1[2*k+1] + b1[k];
            if (hv > 0.f) sum += hv * w2[h * CPBH + k];
        }
        rpb[idx] = 16.0f / (1.0f + __expf(-sum));
    }
}

// ======== 256x256 bf16 MFMA GEMM, double-buffered, COUNTED vmcnt (T4) ========
// C[M][N] = A[M][K] @ Bw[N][K]^T (+bias / gelu / in-place multiply).
// 512 threads = 8 waves (2 M x 4 N), per-wave output 128x64, BK=64.
// LDS 128 KB: As,Bs [2 dbuf][256 rows][64 bf16]. 16B-block XOR swizzle:
//   store LDS[r][s] = G[r][s ^ (r&7)] (achieved by pre-swizzling the GLOBAL
//   source block index, LDS dest linear — rule #21), read slot (blk ^ (r&7)).
// Correctness of the single counted wait (audited):
//   - each K-tile stage = exactly 8 glds16/thread, issued back-to-back;
//   - loop: STAGE(t+1 into buf^1) -> vmcnt(8) completes ALL tile-t loads
//     (only the 8 just-issued may remain) -> barrier -> every wave sees
//     tile-t data -> ds_read/MFMA on buf -> barrier (all waves' reads of
//     buf consumed before next iteration's stage overwrites buf^1... and
//     tile t+2's stage targets buf, which this barrier protects).
//   - no load is ever read in the same phase it was staged.
template<int EPI>
__global__ __launch_bounds__(512, 1) void k_mm256(const u16* __restrict__ A,
                                                  const u16* __restrict__ Bw,
                                                  const float* __restrict__ bias,
                                                  u16* __restrict__ C,
                                                  int K, int N) {
    __shared__ __align__(16) u16 As[2][16384];
    __shared__ __align__(16) u16 Bs[2][16384];
    int t = threadIdx.x;
    int l = t & 63, wv = t >> 6;
    int tn = blockIdx.x << 8, tm = blockIdx.y << 8;
    int wr = wv >> 2, wc = wv & 3;          // wave tile: rows wr*128, cols wc*64
    int fr = l & 15, fk = l >> 4;
    // staging: lane covers row (wv*8 + l>>3) within a 64-row group;
    // fetches global 16B-block (l&7)^(row&7) so linear LDS dest = swizzled store
    int lr8 = l >> 3;
    int kbs = (l & 7) ^ lr8;
    const u16* pA = A  + (size_t)(tm + wv * 8 + lr8) * K + kbs * 8;
    const u16* pB = Bw + (size_t)(tn + wv * 8 + lr8) * K + kbs * 8;
    // frag-read swizzled block offsets (u16 units): block fk (ks=0) / 4+fk (ks=1)
    int rb0 = ((fk ^ (fr & 7)) << 3);
    int rb1 = (((4 + fk) ^ (fr & 7)) << 3);

    f32x4 acc[8][4];
    #pragma unroll
    for (int i = 0; i < 8; ++i)
        #pragma unroll
        for (int j = 0; j < 4; ++j)
            acc[i][j] = (f32x4){0.f, 0.f, 0.f, 0.f};
    bf16x8 Af[4][2], Bf01[2][2], Bf23[2][2];

    // stage half h (128 rows) of K-tile kt into buffer buf (2 glds16)
    #define STG(arr, p, buf, h, kt) do { \
        glds16((p) + (size_t)((h) * 128) * K + (size_t)(kt) * 64, \
               &arr[buf][(h) * 8192 + wv * 512]); \
        glds16((p) + (size_t)((h) * 128 + 64) * K + (size_t)(kt) * 64, \
               &arr[buf][(h) * 8192 + 4096 + wv * 512]); \
    } while (0)
    #define STAGE_TILE(buf, kt) do { \
        STG(As, pA, buf, 0, kt); STG(As, pA, buf, 1, kt); \
        STG(Bs, pB, buf, 0, kt); STG(Bs, pB, buf, 1, kt); \
    } while (0)
    #define LDA(buf, ibase) do { \
        _Pragma("unroll") \
        for (int ii = 0; ii < 4; ++ii) { \
            int ro = (wr * 128 + ((ibase) + ii) * 16 + fr) * 64; \
            Af[ii][0] = *(const bf16x8*)&As[buf][ro + rb0]; \
            Af[ii][1] = *(const bf16x8*)&As[buf][ro + rb1]; \
        } } while (0)
    #define LDB(buf, jbase, dst) do { \
        _Pragma("unroll") \
        for (int jj = 0; jj < 2; ++jj) { \
            int ro = (wc * 64 + ((jbase) + jj) * 16 + fr) * 64; \
            dst[jj][0] = *(const bf16x8*)&Bs[buf][ro + rb0]; \
            dst[jj][1] = *(const bf16x8*)&Bs[buf][ro + rb1]; \
        } } while (0)
    // 32 MFMAs: A rows block (4) x both B col-pairs x 2 k-slots
    #define MFMA32(ib) do { \
        __builtin_amdgcn_s_setprio(1); \
        _Pragma("unroll") \
        for (int ii = 0; ii < 4; ++ii) { \
            _Pragma("unroll") \
            for (int jj = 0; jj < 2; ++jj) \
                _Pragma("unroll") \
                for (int ks = 0; ks < 2; ++ks) { \
                    acc[(ib)+ii][jj]   = __builtin_amdgcn_mfma_f32_16x16x32_bf16( \
                        Af[ii][ks], Bf01[jj][ks], acc[(ib)+ii][jj], 0, 0, 0); \
                    acc[(ib)+ii][2+jj] = __builtin_amdgcn_mfma_f32_16x16x32_bf16( \
                        Af[ii][ks], Bf23[jj][ks], acc[(ib)+ii][2+jj], 0, 0, 0); \
                } \
        } \
        __builtin_amdgcn_s_setprio(0); \
    } while (0)
    #define MEMBAR() do { asm volatile("" ::: "memory"); \
        __builtin_amdgcn_s_barrier(); \
        asm volatile("" ::: "memory"); } while (0)

    STAGE_TILE(0, 0);
    int NK = K >> 6;
    for (int kt = 0; kt < NK; ++kt) {
        int cur = kt & 1;
        if (kt + 1 < NK) {
            STAGE_TILE(cur ^ 1, kt + 1);
            asm volatile("s_waitcnt vmcnt(8)" ::: "memory");
        } else {
            asm volatile("s_waitcnt vmcnt(0)" ::: "memory");
        }
        MEMBAR();                       // tile kt fully visible to all waves
        LDB(cur, 0, Bf01);
        LDB(cur, 2, Bf23);
        LDA(cur, 0);
        MFMA32(0);                      // compiler inserts lgkmcnt for deps
        LDA(cur, 4);
        MFMA32(4);
        MEMBAR();                       // all reads of buf done before overwrite
    }
    #undef STG
    #undef STAGE_TILE
    #undef LDA
    #undef LDB
    #undef MFMA32
    #undef MEMBAR

    // ---- epilogue: C/D layout col = lane&15, row = (lane>>4)*4 + reg ----
    int lr4 = fk << 2;
    #pragma unroll
    for (int j = 0; j < 4; ++j) {
        int col = tn + wc * 64 + j * 16 + fr;
        float bj = bias[col];
        #pragma unroll
        for (int i = 0; i < 8; ++i) {
            int row = tm + wr * 128 + i * 16 + lr4;
            #pragma unroll
            for (int r = 0; r < 4; ++r) {
                size_t idx = (size_t)(row + r) * N + col;
                float v = acc[i][j][r] + bj;
                if (EPI == 0)      C[idx] = f2bf(v);
                else if (EPI == 1) C[idx] = f2bf(gelu_exact(v));
                else               C[idx] = f2bf(bf2f(C[idx]) * v);
            }
        }
    }
}

// ---------------- fused attention per (window, head); bf16 in/out ----------------
__global__ __launch_bounds__(256) void k_attn(const u16* __restrict__ QKV,
                                              const float* __restrict__ rpb,
                                              const float* __restrict__ scale,
                                              u16* __restrict__ outw,
                                              int shift, int w0) {
    __shared__ float smQ[64][100];   // q, later reused for v (pad 100: float4-aligned rows)
    __shared__ float smK[64][100];
    int wl = blockIdx.x >> 3;       // local window
    int wg = w0 + wl;               // global window (for mask region)
    int h = blockIdx.x & 7;
    int t = threadIdx.x;
    const u16* base = QKV + (size_t)wl * NTOK * 2304 + h * HDIM;
    for (int i4 = t; i4 < NTOK * 24; i4 += 256) {
        int nn = i4 / 24, jj = (i4 % 24) * 4;
        const u16* rq = base + (size_t)nn * 2304 + jj;
        ushort4 uq = *(const ushort4*)rq;
        ushort4 uk = *(const ushort4*)(rq + 768);
        float4 fq, fk4;
        fq.x = bf2f(uq.x); fq.y = bf2f(uq.y); fq.z = bf2f(uq.z); fq.w = bf2f(uq.w);
        fk4.x = bf2f(uk.x); fk4.y = bf2f(uk.y); fk4.z = bf2f(uk.z); fk4.w = bf2f(uk.w);
        *(float4*)&smQ[nn][jj] = fq;
        *(float4*)&smK[nn][jj] = fk4;
    }
    __syncthreads();
    if (t < 128) {
        int row = t & 63;
        float4* rp4 = (t < 64) ? (float4*)smQ[row] : (float4*)smK[row];
        float ss = 0.f;
        #pragma unroll
        for (int jj = 0; jj < 24; ++jj) {
            float4 v = rp4[jj];
            ss += v.x * v.x + v.y * v.y + v.z * v.z + v.w * v.w;
        }
        float rn = 1.0f / fmaxf(sqrtf(ss), 1e-12f);
        if (t < 64) rn *= scale[h];
        #pragma unroll
        for (int jj = 0; jj < 24; ++jj) {
            float4 v = rp4[jj];
            v.x *= rn; v.y *= rn; v.z *= rn; v.w *= rn;
            rp4[jj] = v;
        }
    }
    __syncthreads();
    int n = t >> 2, m0q = (t & 3) << 4;
    int p1 = n >> 3, q1 = n & 7;
    int idn = 0, hi = 0, wi = 0;
    if (shift) {
        int wim = wg & 127; hi = wim >> 4; wi = wim & 15;
        idn = reg_r(hi * 8 + p1) * 3 + reg_c(wi * 8 + q1);
    }
    float4 qv[24];
    #pragma unroll
    for (int jj = 0; jj < 24; ++jj) qv[jj] = *(const float4*)&smQ[n][jj * 4];
    float P[16];
    #pragma unroll 1
    for (int s = 0; s < 16; ++s) {
        int mm = m0q + s;
        const float4* kr = (const float4*)&smK[mm][0];
        float acc = 0.f;
        #pragma unroll
        for (int jj = 0; jj < 24; ++jj) {
            float4 a = qv[jj], b = kr[jj];
            acc = fmaf(a.x, b.x, acc); acc = fmaf(a.y, b.y, acc);
            acc = fmaf(a.z, b.z, acc); acc = fmaf(a.w, b.w, acc);
        }
        int p2 = mm >> 3, q2 = mm & 7;
        acc += rpb[((p1 - p2 + 7) * 15 + (q1 - q2 + 7)) * NHEADS + h];
        if (shift) {
            int idm = reg_r(hi * 8 + p2) * 3 + reg_c(wi * 8 + q2);
            if (idm != idn) acc -= 100.0f;
        }
        P[s] = acc;
    }
    float mx = P[0];
    #pragma unroll
    for (int s = 1; s < 16; ++s) mx = fmaxf(mx, P[s]);
    mx = fmaxf(mx, __shfl_xor(mx, 1));
    mx = fmaxf(mx, __shfl_xor(mx, 2));
    float sum = 0.f;
    #pragma unroll
    for (int s = 0; s < 16; ++s) { P[s] = __expf(P[s] - mx); sum += P[s]; }
    sum += __shfl_xor(sum, 1);
    sum += __shfl_xor(sum, 2);
    float inv = 1.0f / sum;
    #pragma unroll
    for (int s = 0; s < 16; ++s) P[s] *= inv;
    __syncthreads();   // done reading q
    for (int i4 = t; i4 < NTOK * 24; i4 += 256) {
        int nn = i4 / 24, jj = (i4 % 24) * 4;
        ushort4 uv = *(const ushort4*)(base + (size_t)nn * 2304 + 1536 + jj);
        float4 fv;
        fv.x = bf2f(uv.x); fv.y = bf2f(uv.y); fv.z = bf2f(uv.z); fv.w = bf2f(uv.w);
        *(float4*)&smQ[nn][jj] = fv;   // v
    }
    __syncthreads();
    u16* orow = outw + ((size_t)wl * NTOK + n) * CDIM + h * HDIM;
    #pragma unroll 1
    for (int c0 = 0; c0 < HDIM; c0 += 24) {
        float4 part[6];
        #pragma unroll
        for (int jj = 0; jj < 6; ++jj) { part[jj].x = 0.f; part[jj].y = 0.f; part[jj].z = 0.f; part[jj].w = 0.f; }
        #pragma unroll 1
        for (int s = 0; s < 16; ++s) {
            float pv = P[s];
            const float4* vr = (const float4*)&smQ[m0q + s][c0];
            #pragma unroll
            for (int jj = 0; jj < 6; ++jj) {
                float4 v4 = vr[jj];
                part[jj].x = fmaf(pv, v4.x, part[jj].x);
                part[jj].y = fmaf(pv, v4.y, part[jj].y);
                part[jj].z = fmaf(pv, v4.z, part[jj].z);
                part[jj].w = fmaf(pv, v4.w, part[jj].w);
            }
        }
        #pragma unroll
        for (int jj = 0; jj < 6; ++jj) {
            part[jj].x += __shfl_xor(part[jj].x, 1); part[jj].x += __shfl_xor(part[jj].x, 2);
            part[jj].y += __shfl_xor(part[jj].y, 1); part[jj].y += __shfl_xor(part[jj].y, 2);
            part[jj].z += __shfl_xor(part[jj].z, 1); part[jj].z += __shfl_xor(part[jj].z, 2);
            part[jj].w += __shfl_xor(part[jj].w, 1); part[jj].w += __shfl_xor(part[jj].w, 2);
        }
        if ((t & 3) == (c0 / 24)) {
            u16 tmp[24];
            #pragma unroll
            for (int jj = 0; jj < 6; ++jj) {
                tmp[jj*4+0] = f2bf(part[jj].x); tmp[jj*4+1] = f2bf(part[jj].y);
                tmp[jj*4+2] = f2bf(part[jj].z); tmp[jj*4+3] = f2bf(part[jj].w);
            }
            *(uint4*)&orow[c0]      = *(const uint4*)&tmp[0];
            *(uint4*)&orow[c0 + 8]  = *(const uint4*)&tmp[8];
            *(uint4*)&orow[c0 + 16] = *(const uint4*)&tmp[16];
        }
    }
}

// ---------------- chunked LayerNorm + residual: X[target] += LN(Yc[lm])*g + b ----------------
__global__ __launch_bounds__(256) void k_ln_add(float* __restrict__ X,
                                                const u16* __restrict__ Yc,
                                                const float* __restrict__ g,
                                                const float* __restrict__ bb,
                                                int m0, int shift, int winmap) {
    int lm = blockIdx.x;
    int gm = m0 + lm;
    int target;
    if (winmap) {
        int w = gm >> 6, n = gm & 63;
        int b = w >> 7, wim = w & 127, hi = wim >> 4, wi = wim & 15;
        int p = n >> 3, q = n & 7;
        int r  = (hi * 8 + p + shift) & (HRES - 1);
        int cc = (wi * 8 + q + shift) & (WRES - 1);
        target = (b * HRES + r) * WRES + cc;
    } else {
        target = gm;
    }
    size_t xo = (size_t)target * CDIM;
    size_t yo = (size_t)lm * CDIM;
    int t = threadIdx.x;
    float v0 = bf2f(Yc[yo + t]), v1 = bf2f(Yc[yo + t + 256]), v2 = bf2f(Yc[yo + t + 512]);
    float s = v0 + v1 + v2;
    float ss = v0*v0 + v1*v1 + v2*v2;
    #pragma unroll
    for (int o = 32; o > 0; o >>= 1) {
        s  += __shfl_down(s, o);
        ss += __shfl_down(ss, o);
    }
    __shared__ float rs_[4], rss_[4];
    if ((t & 63) == 0) { rs_[t >> 6] = s; rss_[t >> 6] = ss; }
    __syncthreads();
    float S  = rs_[0] + rs_[1] + rs_[2] + rs_[3];
    float SS = rss_[0] + rss_[1] + rss_[2] + rss_[3];
    float mu = S * (1.0f / CDIM);
    float var = SS * (1.0f / CDIM) - mu * mu;
    float rstd = rsqrtf(fmaxf(var, 0.0f) + 1e-5f);
    X[xo + t]       += (v0 - mu) * rstd * g[t]       + bb[t];
    X[xo + t + 256] += (v1 - mu) * rstd * g[t + 256] + bb[t + 256];
    X[xo + t + 512] += (v2 - mu) * rstd * g[t + 512] + bb[t + 512];
}

// ---------------- host launcher ----------------
extern "C" void kernel_launch(void* const* d_in, const int* in_sizes, int n_in,
                              void* d_out, int out_size, void* d_ws, size_t ws_size,
                              hipStream_t stream) {
    (void)in_sizes; (void)n_in; (void)out_size;
    const float* x_in  = (const float*)d_in[0];
    const float* n1g   = (const float*)d_in[1];
    const float* n1b   = (const float*)d_in[2];
    const float* n2g   = (const float*)d_in[3];
    const float* n2b   = (const float*)d_in[4];
    const float* qkvw  = (const float*)d_in[5];
    const float* qbias = (const float*)d_in[6];
    const float* vbias = (const float*)d_in[7];
    const float* lscal = (const float*)d_in[8];
    const float* cpbw1 = (const float*)d_in[9];
    const float* cpbb1 = (const float*)d_in[10];
    const float* cpbw2 = (const float*)d_in[11];
    const float* projw = (const float*)d_in[12];
    const float* projb = (const float*)d_in[13];
    const float* fc1w  = (const float*)d_in[14];
    const float* fc1b  = (const float*)d_in[15];
    const float* fc2w  = (const float*)d_in[16];
    const float* fc2b  = (const float*)d_in[17];

    // residual stream X lives in d_out (fp32, MTOT*CDIM elements)
    float* X = (float*)d_out;

    // ---- ws layout: header 32 KB | bf16 weights (per depth) | chunk scratch ----
    float* RPB  = (float*)d_ws;                    // 1800 floats
    float* SCAL = RPB + 1800;                      // 8 floats
    float* QKVB = RPB + 1808;                      // 2304 floats (combined qkv bias)
    u16* Wq = (u16*)((char*)d_ws + 32768);         // 2304*768
    u16* Wp = Wq + 2304 * 768;                     // 768*768
    u16* W1 = Wp + 768 * 768;                      // 6144*768
    u16* W2 = W1 + 6144 * 768;                     // 768*3072
    u16* SCR = W2 + 768 * 3072;                    // chunk scratch

    // per-row scratch (uniform for both phases): 4608 u16 = 9216 B
    //  MLP : Xb(768) | Hg(3072) | Yc(768)
    //  attn: Xw(768) | QKV(2304)+OUTW(768) in Hg region | Yc(768)
    long long avail = (long long)ws_size - 32768 - 18874368;
    if (avail < 0) avail = 0;
    long long mc_ll = (avail / 9216) & ~255LL;
    int Mc = (int)(mc_ll < 256 ? 256 : (mc_ll > MTOT ? MTOT : mc_ll));

    u16* Xb   = SCR;                               // Mc*768
    u16* Hg   = Xb + (size_t)Mc * 768;             // Mc*3072
    u16* Yc   = Hg + (size_t)Mc * 3072;            // Mc*768
    u16* QKV  = Hg;                                // alias: Mc*2304
    u16* OUTW = Hg + (size_t)Mc * 2304;            // alias: Mc*768

    // copy input -> residual (fp32, 16B vectors)
    k_copy<<<(MTOT * CDIM) / 1024, 256, 0, stream>>>((const float4*)x_in, (float4*)X);

    for (int d = 0; d < 2; ++d) {
        int shift = d ? 4 : 0;
        // per-depth weight conversion to bf16 (tiny vs GEMM time)
        k_cvt<<<(2304*768/4 + 255)/256, 256, 0, stream>>>(
            (const float4*)(qkvw + (size_t)d * 2304 * 768), (ushort4*)Wq, 2304*768/4);
        k_cvt<<<(768*768/4 + 255)/256, 256, 0, stream>>>(
            (const float4*)(projw + (size_t)d * 768 * 768), (ushort4*)Wp, 768*768/4);
        k_cvt<<<(6144*768/4 + 255)/256, 256, 0, stream>>>(
            (const float4*)(fc1w + (size_t)d * 6144 * 768), (ushort4*)W1, 6144*768/4);
        k_cvt<<<(768*3072/4 + 255)/256, 256, 0, stream>>>(
            (const float4*)(fc2w + (size_t)d * 768 * 3072), (ushort4*)W2, 768*3072/4);
        k_qkvb<<<9, 256, 0, stream>>>(qbias + d * 768, vbias + d * 768, QKVB);
        k_cpb<<<1, 256, 0, stream>>>(cpbw1 + d * 1024, cpbb1 + d * 512,
                                     cpbw2 + d * 4096, lscal + d * 8, RPB, SCAL);
        // ---- attention branch, chunked (chunks touch disjoint X rows) ----
        for (int m0 = 0; m0 < MTOT; m0 += Mc) {
            int cur = (MTOT - m0) < Mc ? (MTOT - m0) : Mc;
            k_xcvt<<<cur, 192, 0, stream>>>(X, Xb, m0, shift, 1);
            k_mm256<0><<<dim3(2304 / 256, cur / 256), 512, 0, stream>>>(
                Xb, Wq, QKVB, QKV, 768, 2304);
            k_attn<<<(cur / 64) * NHEADS, 256, 0, stream>>>(QKV, RPB, SCAL, OUTW,
                                                            shift, m0 / 64);
            k_mm256<0><<<dim3(768 / 256, cur / 256), 512, 0, stream>>>(
                OUTW, Wp, projb + d * 768, Yc, 768, 768);
            k_ln_add<<<cur, 256, 0, stream>>>(X, Yc, n1g + d * 768, n1b + d * 768,
                                              m0, shift, 1);
        }
        // ---- MLP branch, chunked ----
        for (int m0 = 0; m0 < MTOT; m0 += Mc) {
            int cur = (MTOT - m0) < Mc ? (MTOT - m0) : Mc;
            k_xcvt<<<cur, 192, 0, stream>>>(X, Xb, m0, 0, 0);
            // gate half: Hg = gelu(X@Wg^T + bg)
            k_mm256<1><<<dim3(3072 / 256, cur / 256), 512, 0, stream>>>(
                Xb, W1, fc1b + d * 6144, Hg, 768, 3072);
            // val half: Hg *= (X@Wv^T + bv)
            k_mm256<2><<<dim3(3072 / 256, cur / 256), 512, 0, stream>>>(
                Xb, W1 + (size_t)3072 * 768, fc1b + d * 6144 + 3072, Hg, 768, 3072);
            k_mm256<0><<<dim3(768 / 256, cur / 256), 512, 0, stream>>>(
                Hg, W2, fc2b + d * 768, Yc, 3072, 768);
            k_ln_add<<<cur, 256, 0, stream>>>(X, Yc, n2g + d * 768, n2b + d * 768,
                                              m0, 0, 0);
        }
    }
}

// Round 5
// 4004.382 us; speedup vs baseline: 4.6422x; 1.1089x over previous
//
#include <hip/hip_runtime.h>
#include <hip/hip_bf16.h>
#include <math.h>

// ---------------- problem constants ----------------
#define HRES   64
#define WRES   128
#define CDIM   768
#define NHEADS 8
#define WINSZ  8
#define NTOK   64          // WINSZ*WINSZ
#define HDIM   96          // CDIM/NHEADS
#define HIDDIM 3072
#define NWH    8           // HRES/WINSZ
#define NWW    16          // WRES/WINSZ
#define NWIMG  128         // NWH*NWW
#define NWTOT  512         // B*NWIMG
#define MTOT   32768       // NWTOT*NTOK
#define CPBH   512

typedef unsigned short u16;
typedef __attribute__((ext_vector_type(8))) short bf16x8;   // 8 bf16 in 4 VGPRs
typedef __attribute__((ext_vector_type(4))) float f32x4;

__device__ __forceinline__ float bf2f(u16 u) {
    return __uint_as_float(((unsigned)u) << 16);
}
__device__ __forceinline__ u16 f2bf(float f) {
    unsigned u = __float_as_uint(f);
    u += 0x7FFFu + ((u >> 16) & 1u);
    return (u16)(u >> 16);
}
__device__ __forceinline__ float gelu_exact(float x) {
    return 0.5f * x * (1.0f + erff(x * 0.70710678118654752f));
}
__device__ __forceinline__ int reg_r(int r) { return r < HRES-8 ? 0 : (r < HRES-4 ? 1 : 2); }
__device__ __forceinline__ int reg_c(int c) { return c < WRES-8 ? 0 : (c < WRES-4 ? 1 : 2); }

// async global -> LDS, 16 bytes per lane; lds base must be wave-uniform
__device__ __forceinline__ void glds16(const u16* g, u16* l) {
    __builtin_amdgcn_global_load_lds(
        (const __attribute__((address_space(1))) void*)g,
        (__attribute__((address_space(3))) void*)l, 16, 0, 0);
}

// ---------------- fp32 copy input -> residual X (in d_out) ----------------
__global__ __launch_bounds__(256) void k_copy(const float4* __restrict__ in,
                                              float4* __restrict__ out) {
    size_t i = (size_t)blockIdx.x * 256 + threadIdx.x;
    out[i] = in[i];
}

// ---------------- generic fp32 -> bf16 conversion (weights) ----------------
__global__ __launch_bounds__(256) void k_cvt(const float4* __restrict__ in,
                                             ushort4* __restrict__ out, int n4) {
    int i = blockIdx.x * 256 + threadIdx.x;
    if (i < n4) {
        float4 v = in[i];
        ushort4 o;
        o.x = f2bf(v.x); o.y = f2bf(v.y); o.z = f2bf(v.z); o.w = f2bf(v.w);
        out[i] = o;
    }
}

// ---------------- build combined qkv bias (q | 0 | v), fp32 ----------------
__global__ __launch_bounds__(256) void k_qkvb(const float* __restrict__ qb,
                                              const float* __restrict__ vb,
                                              float* __restrict__ dst) {
    int i = blockIdx.x * 256 + threadIdx.x;
    if (i < 2304)
        dst[i] = (i < 768) ? qb[i] : ((i < 1536) ? 0.f : vb[i - 1536]);
}

// ---------------- X rows -> bf16 rows, optional shifted-window gather ----------------
__global__ __launch_bounds__(192) void k_xcvt(const float* __restrict__ X,
                                              u16* __restrict__ out,
                                              int m0, int shift, int winmap) {
    int lm = blockIdx.x, t = threadIdx.x;
    int gm = m0 + lm;
    int src;
    if (winmap) {
        int w = gm >> 6, n = gm & 63;
        int b = w >> 7, wim = w & 127, hi = wim >> 4, wi = wim & 15;
        int p = n >> 3, q = n & 7;
        int r  = (hi * 8 + p + shift) & (HRES - 1);
        int cc = (wi * 8 + q + shift) & (WRES - 1);
        src = (b * HRES + r) * WRES + cc;
    } else {
        src = gm;
    }
    float4 v = *(const float4*)(X + (size_t)src * CDIM + t * 4);
    ushort4 o;
    o.x = f2bf(v.x); o.y = f2bf(v.y); o.z = f2bf(v.z); o.w = f2bf(v.w);
    *(ushort4*)(out + (size_t)lm * CDIM + t * 4) = o;
}

// ---------------- CPB MLP: rpb table (225 x 8) + per-head scale ----------------
__global__ __launch_bounds__(256) void k_cpb(const float* __restrict__ w1,
                                             const float* __restrict__ b1,
                                             const float* __restrict__ w2,
                                             const float* __restrict__ ls,
                                             float* __restrict__ rpb,
                                             float* __restrict__ scale) {
    int t = threadIdx.x;
    if (t < NHEADS) scale[t] = __expf(fminf(ls[t], 4.6051701859880914f)); // ln(100)
    for (int idx = t; idx < 225 * NHEADS; idx += 256) {
        int tt = idx >> 3, h = idx & 7;
        int i = tt / 15, j = tt % 15;
        float vi = 8.0f * (float)(i - 7) / 7.0f;
        float vj = 8.0f * (float)(j - 7) / 7.0f;
        float si = (vi > 0.f) ? 1.f : ((vi < 0.f) ? -1.f : 0.f);
        float sj = (vj > 0.f) ? 1.f : ((vj < 0.f) ? -1.f : 0.f);
        float c0 = si * log2f(fabsf(vi) + 1.0f) * (1.0f / 3.0f);
        float c1 = sj * log2f(fabsf(vj) + 1.0f) * (1.0f / 3.0f);
        float sum = 0.f;
        for (int k = 0; k < CPBH; ++k) {
            float hv = c0 * w1[2*k] + c1 * w1[2*k+1] + b1[k];
            if (hv > 0.f) sum += hv * w2[h * CPBH + k];
        }
        rpb[idx] = 16.0f / (1.0f + __expf(-sum));
    }
}

// ======== 128x128 bf16 MFMA GEMM, dbuf + counted vmcnt, 2 blocks/CU ========
// C[M][N] = A[M][K] @ Bw[N][K]^T (+bias / gelu / in-place multiply).
// 256 threads = 4 waves, per-wave output 64x64 quadrant, BK=64.
// LDS 64 KB: As,Bs [2 dbuf][128 rows][64 bf16] -> 2 blocks/CU (TLP covers
// latency the 1-deep pipeline can't). 16B-block XOR swizzle as round 3
// (store G[r][s^(r&7)] via pre-swizzled GLOBAL block index, linear LDS dest;
// read block (fk|4+fk)^(r&7)) -> verified 0 bank conflicts.
// Counted-wait audit (same proof as round 3, which passed):
//   stage = exactly 8 glds16/wave; loop: STAGE(t+1,buf^1) -> vmcnt(8)
//   (completes ALL tile-t loads, only the 8 just issued remain) -> barrier ->
//   read/MFMA buf -> barrier. No load read in the phase it was staged.
// Epilogue: acc -> LDS (bf16) -> coalesced ushort8 row stores (full lines,
// no RMW; round-3 wrote 2B-scattered: WRITE 293MB vs 201 ideal).
// Bijective XCD chunking (m204) so N-tile blocks sharing an A-panel land on
// the same XCD L2 (round-3 FETCH 511MB ~= A re-fetched per XCD).
template<int EPI>
__global__ __launch_bounds__(256, 2) void k_mm128(const u16* __restrict__ A,
                                                  const u16* __restrict__ Bw,
                                                  const float* __restrict__ bias,
                                                  u16* __restrict__ C,
                                                  int K, int N) {
    __shared__ __align__(16) u16 As[2][8192];   // [128][64] per buffer
    __shared__ __align__(16) u16 Bs[2][8192];
    int t = threadIdx.x;
    int l = t & 63, wv = t >> 6;
    // ---- bijective XCD chunk remap (consecutive HW ids share an XCD slab)
    int gx = gridDim.x;
    int nb = gx * gridDim.y;
    int b  = blockIdx.y * gx + blockIdx.x;
    int q8 = nb >> 3, r8 = nb & 7, x8 = b & 7, o8 = b >> 3;
    int v  = (x8 < r8 ? x8 * (q8 + 1) : r8 * (q8 + 1) + (x8 - r8) * q8) + o8;
    int tn = (v % gx) << 7, tm = (v / gx) << 7;
    // wave quadrant
    int wr = wv >> 1, wc = wv & 1;
    int r0 = wr << 6, c0 = wc << 6;
    int fr = l & 15, fk = l >> 4;
    // staging: wave wv covers rows [wv*32, wv*32+32), 4 issues of 8 rows each,
    // lane fetches global 16B-block (l&7)^(l>>3) -> linear LDS = swizzled store
    int lr8 = l >> 3;
    int kbs = (l & 7) ^ lr8;
    const u16* pA = A  + (size_t)(tm + wv * 32 + lr8) * K + kbs * 8;
    const u16* pB = Bw + (size_t)(tn + wv * 32 + lr8) * K + kbs * 8;
    // frag-read swizzled block offsets (u16 units)
    int rb0 = ((fk ^ (fr & 7)) << 3);
    int rb1 = (((4 + fk) ^ (fr & 7)) << 3);

    f32x4 acc[4][4];
    #pragma unroll
    for (int i = 0; i < 4; ++i)
        #pragma unroll
        for (int j = 0; j < 4; ++j)
            acc[i][j] = (f32x4){0.f, 0.f, 0.f, 0.f};
    bf16x8 Af[4][2], Bf[4][2];

    #define STG(arr, p, buf, h, kt) \
        glds16((p) + (size_t)((h) * 8) * K + (size_t)(kt) * 64, \
               &arr[buf][(wv << 11) + ((h) << 9)])
    #define STAGE_TILE(buf, kt) do { \
        STG(As, pA, buf, 0, kt); STG(As, pA, buf, 1, kt); \
        STG(As, pA, buf, 2, kt); STG(As, pA, buf, 3, kt); \
        STG(Bs, pB, buf, 0, kt); STG(Bs, pB, buf, 1, kt); \
        STG(Bs, pB, buf, 2, kt); STG(Bs, pB, buf, 3, kt); \
    } while (0)
    #define LDFRAG(buf) do { \
        _Pragma("unroll") \
        for (int ii = 0; ii < 4; ++ii) { \
            int roA = (r0 + ii * 16 + fr) << 6; \
            int roB = (c0 + ii * 16 + fr) << 6; \
            Af[ii][0] = *(const bf16x8*)&As[buf][roA + rb0]; \
            Af[ii][1] = *(const bf16x8*)&As[buf][roA + rb1]; \
            Bf[ii][0] = *(const bf16x8*)&Bs[buf][roB + rb0]; \
            Bf[ii][1] = *(const bf16x8*)&Bs[buf][roB + rb1]; \
        } } while (0)
    #define MEMBAR() do { asm volatile("" ::: "memory"); \
        __builtin_amdgcn_s_barrier(); \
        asm volatile("" ::: "memory"); } while (0)

    STAGE_TILE(0, 0);
    int NK = K >> 6;
    for (int kt = 0; kt < NK; ++kt) {
        int cur = kt & 1;
        if (kt + 1 < NK) {
            STAGE_TILE(cur ^ 1, kt + 1);
            asm volatile("s_waitcnt vmcnt(8)" ::: "memory");
        } else {
            asm volatile("s_waitcnt vmcnt(0)" ::: "memory");
        }
        MEMBAR();                       // tile kt fully visible to all waves
        LDFRAG(cur);
        __builtin_amdgcn_s_setprio(1);
        #pragma unroll
        for (int ii = 0; ii < 4; ++ii)
            #pragma unroll
            for (int jj = 0; jj < 4; ++jj)
                #pragma unroll
                for (int ks = 0; ks < 2; ++ks)
                    acc[ii][jj] = __builtin_amdgcn_mfma_f32_16x16x32_bf16(
                        Af[ii][ks], Bf[jj][ks], acc[ii][jj], 0, 0, 0);
        __builtin_amdgcn_s_setprio(0);
        MEMBAR();                       // all reads of buf done before overwrite
    }
    #undef STG
    #undef STAGE_TILE
    #undef LDFRAG
    #undef MEMBAR

    // ---- epilogue: acc -> LDS (bf16 tile [128][128]) -> coalesced stores ----
    // C/D layout: col = lane&15, row = (lane>>4)*4 + reg  [verified m89]
    u16* Cs = (u16*)As;   // 32 KB = 128*128 u16, safe: loop ended with barrier
    float bj[4];
    #pragma unroll
    for (int j = 0; j < 4; ++j) bj[j] = bias[tn + c0 + j * 16 + fr];
    #pragma unroll
    for (int i = 0; i < 4; ++i) {
        int row = r0 + i * 16 + (fk << 2);
        #pragma unroll
        for (int j = 0; j < 4; ++j) {
            int col = c0 + j * 16 + fr;
            #pragma unroll
            for (int r = 0; r < 4; ++r) {
                float vv = acc[i][j][r] + bj[j];
                if (EPI == 1) vv = gelu_exact(vv);
                Cs[(row + r) * 128 + col] = f2bf(vv);
            }
        }
    }
    __syncthreads();
    #pragma unroll
    for (int p = 0; p < 8; ++p) {
        int idx = p * 2048 + t * 8;
        int row = idx >> 7, col = idx & 127;
        ushort4 lo = *(const ushort4*)&Cs[idx];
        ushort4 hi = *(const ushort4*)&Cs[idx + 4];
        u16* gp = &C[(size_t)(tm + row) * N + tn + col];
        if (EPI == 2) {
            ushort4 ol = *(const ushort4*)gp;
            ushort4 oh = *(const ushort4*)(gp + 4);
            lo.x = f2bf(bf2f(ol.x) * bf2f(lo.x)); lo.y = f2bf(bf2f(ol.y) * bf2f(lo.y));
            lo.z = f2bf(bf2f(ol.z) * bf2f(lo.z)); lo.w = f2bf(bf2f(ol.w) * bf2f(lo.w));
            hi.x = f2bf(bf2f(oh.x) * bf2f(hi.x)); hi.y = f2bf(bf2f(oh.y) * bf2f(hi.y));
            hi.z = f2bf(bf2f(oh.z) * bf2f(hi.z)); hi.w = f2bf(bf2f(oh.w) * bf2f(hi.w));
        }
        *(ushort4*)gp       = lo;
        *(ushort4*)(gp + 4) = hi;
    }
}

// ---------------- fused attention per (window, head); bf16 in/out ----------------
__global__ __launch_bounds__(256) void k_attn(const u16* __restrict__ QKV,
                                              const float* __restrict__ rpb,
                                              const float* __restrict__ scale,
                                              u16* __restrict__ outw,
                                              int shift, int w0) {
    __shared__ float smQ[64][100];   // q, later reused for v (pad 100: float4-aligned rows)
    __shared__ float smK[64][100];
    int wl = blockIdx.x >> 3;       // local window
    int wg = w0 + wl;               // global window (for mask region)
    int h = blockIdx.x & 7;
    int t = threadIdx.x;
    const u16* base = QKV + (size_t)wl * NTOK * 2304 + h * HDIM;
    for (int i4 = t; i4 < NTOK * 24; i4 += 256) {
        int nn = i4 / 24, jj = (i4 % 24) * 4;
        const u16* rq = base + (size_t)nn * 2304 + jj;
        ushort4 uq = *(const ushort4*)rq;
        ushort4 uk = *(const ushort4*)(rq + 768);
        float4 fq, fk4;
        fq.x = bf2f(uq.x); fq.y = bf2f(uq.y); fq.z = bf2f(uq.z); fq.w = bf2f(uq.w);
        fk4.x = bf2f(uk.x); fk4.y = bf2f(uk.y); fk4.z = bf2f(uk.z); fk4.w = bf2f(uk.w);
        *(float4*)&smQ[nn][jj] = fq;
        *(float4*)&smK[nn][jj] = fk4;
    }
    __syncthreads();
    if (t < 128) {
        int row = t & 63;
        float4* rp4 = (t < 64) ? (float4*)smQ[row] : (float4*)smK[row];
        float ss = 0.f;
        #pragma unroll
        for (int jj = 0; jj < 24; ++jj) {
            float4 v = rp4[jj];
            ss += v.x * v.x + v.y * v.y + v.z * v.z + v.w * v.w;
        }
        float rn = 1.0f / fmaxf(sqrtf(ss), 1e-12f);
        if (t < 64) rn *= scale[h];
        #pragma unroll
        for (int jj = 0; jj < 24; ++jj) {
            float4 v = rp4[jj];
            v.x *= rn; v.y *= rn; v.z *= rn; v.w *= rn;
            rp4[jj] = v;
        }
    }
    __syncthreads();
    int n = t >> 2, m0q = (t & 3) << 4;
    int p1 = n >> 3, q1 = n & 7;
    int idn = 0, hi = 0, wi = 0;
    if (shift) {
        int wim = wg & 127; hi = wim >> 4; wi = wim & 15;
        idn = reg_r(hi * 8 + p1) * 3 + reg_c(wi * 8 + q1);
    }
    float4 qv[24];
    #pragma unroll
    for (int jj = 0; jj < 24; ++jj) qv[jj] = *(const float4*)&smQ[n][jj * 4];
    float P[16];
    #pragma unroll 1
    for (int s = 0; s < 16; ++s) {
        int mm = m0q + s;
        const float4* kr = (const float4*)&smK[mm][0];
        float acc = 0.f;
        #pragma unroll
        for (int jj = 0; jj < 24; ++jj) {
            float4 a = qv[jj], b = kr[jj];
            acc = fmaf(a.x, b.x, acc); acc = fmaf(a.y, b.y, acc);
            acc = fmaf(a.z, b.z, acc); acc = fmaf(a.w, b.w, acc);
        }
        int p2 = mm >> 3, q2 = mm & 7;
        acc += rpb[((p1 - p2 + 7) * 15 + (q1 - q2 + 7)) * NHEADS + h];
        if (shift) {
            int idm = reg_r(hi * 8 + p2) * 3 + reg_c(wi * 8 + q2);
            if (idm != idn) acc -= 100.0f;
        }
        P[s] = acc;
    }
    float mx = P[0];
    #pragma unroll
    for (int s = 1; s < 16; ++s) mx = fmaxf(mx, P[s]);
    mx = fmaxf(mx, __shfl_xor(mx, 1));
    mx = fmaxf(mx, __shfl_xor(mx, 2));
    float sum = 0.f;
    #pragma unroll
    for (int s = 0; s < 16; ++s) { P[s] = __expf(P[s] - mx); sum += P[s]; }
    sum += __shfl_xor(sum, 1);
    sum += __shfl_xor(sum, 2);
    float inv = 1.0f / sum;
    #pragma unroll
    for (int s = 0; s < 16; ++s) P[s] *= inv;
    __syncthreads();   // done reading q
    for (int i4 = t; i4 < NTOK * 24; i4 += 256) {
        int nn = i4 / 24, jj = (i4 % 24) * 4;
        ushort4 uv = *(const ushort4*)(base + (size_t)nn * 2304 + 1536 + jj);
        float4 fv;
        fv.x = bf2f(uv.x); fv.y = bf2f(uv.y); fv.z = bf2f(uv.z); fv.w = bf2f(uv.w);
        *(float4*)&smQ[nn][jj] = fv;   // v
    }
    __syncthreads();
    u16* orow = outw + ((size_t)wl * NTOK + n) * CDIM + h * HDIM;
    #pragma unroll 1
    for (int c0 = 0; c0 < HDIM; c0 += 24) {
        float4 part[6];
        #pragma unroll
        for (int jj = 0; jj < 6; ++jj) { part[jj].x = 0.f; part[jj].y = 0.f; part[jj].z = 0.f; part[jj].w = 0.f; }
        #pragma unroll 1
        for (int s = 0; s < 16; ++s) {
            float pv = P[s];
            const float4* vr = (const float4*)&smQ[m0q + s][c0];
            #pragma unroll
            for (int jj = 0; jj < 6; ++jj) {
                float4 v4 = vr[jj];
                part[jj].x = fmaf(pv, v4.x, part[jj].x);
                part[jj].y = fmaf(pv, v4.y, part[jj].y);
                part[jj].z = fmaf(pv, v4.z, part[jj].z);
                part[jj].w = fmaf(pv, v4.w, part[jj].w);
            }
        }
        #pragma unroll
        for (int jj = 0; jj < 6; ++jj) {
            part[jj].x += __shfl_xor(part[jj].x, 1); part[jj].x += __shfl_xor(part[jj].x, 2);
            part[jj].y += __shfl_xor(part[jj].y, 1); part[jj].y += __shfl_xor(part[jj].y, 2);
            part[jj].z += __shfl_xor(part[jj].z, 1); part[jj].z += __shfl_xor(part[jj].z, 2);
            part[jj].w += __shfl_xor(part[jj].w, 1); part[jj].w += __shfl_xor(part[jj].w, 2);
        }
        if ((t & 3) == (c0 / 24)) {
            u16 tmp[24];
            #pragma unroll
            for (int jj = 0; jj < 6; ++jj) {
                tmp[jj*4+0] = f2bf(part[jj].x); tmp[jj*4+1] = f2bf(part[jj].y);
                tmp[jj*4+2] = f2bf(part[jj].z); tmp[jj*4+3] = f2bf(part[jj].w);
            }
            *(uint4*)&orow[c0]      = *(const uint4*)&tmp[0];
            *(uint4*)&orow[c0 + 8]  = *(const uint4*)&tmp[8];
            *(uint4*)&orow[c0 + 16] = *(const uint4*)&tmp[16];
        }
    }
}

// ---------------- chunked LayerNorm + residual: X[target] += LN(Yc[lm])*g + b ----------------
__global__ __launch_bounds__(256) void k_ln_add(float* __restrict__ X,
                                                const u16* __restrict__ Yc,
                                                const float* __restrict__ g,
                                                const float* __restrict__ bb,
                                                int m0, int shift, int winmap) {
    int lm = blockIdx.x;
    int gm = m0 + lm;
    int target;
    if (winmap) {
        int w = gm >> 6, n = gm & 63;
        int b = w >> 7, wim = w & 127, hi = wim >> 4, wi = wim & 15;
        int p = n >> 3, q = n & 7;
        int r  = (hi * 8 + p + shift) & (HRES - 1);
        int cc = (wi * 8 + q + shift) & (WRES - 1);
        target = (b * HRES + r) * WRES + cc;
    } else {
        target = gm;
    }
    size_t xo = (size_t)target * CDIM;
    size_t yo = (size_t)lm * CDIM;
    int t = threadIdx.x;
    float v0 = bf2f(Yc[yo + t]), v1 = bf2f(Yc[yo + t + 256]), v2 = bf2f(Yc[yo + t + 512]);
    float s = v0 + v1 + v2;
    float ss = v0*v0 + v1*v1 + v2*v2;
    #pragma unroll
    for (int o = 32; o > 0; o >>= 1) {
        s  += __shfl_down(s, o);
        ss += __shfl_down(ss, o);
    }
    __shared__ float rs_[4], rss_[4];
    if ((t & 63) == 0) { rs_[t >> 6] = s; rss_[t >> 6] = ss; }
    __syncthreads();
    float S  = rs_[0] + rs_[1] + rs_[2] + rs_[3];
    float SS = rss_[0] + rss_[1] + rss_[2] + rss_[3];
    float mu = S * (1.0f / CDIM);
    float var = SS * (1.0f / CDIM) - mu * mu;
    float rstd = rsqrtf(fmaxf(var, 0.0f) + 1e-5f);
    X[xo + t]       += (v0 - mu) * rstd * g[t]       + bb[t];
    X[xo + t + 256] += (v1 - mu) * rstd * g[t + 256] + bb[t + 256];
    X[xo + t + 512] += (v2 - mu) * rstd * g[t + 512] + bb[t + 512];
}

// ---------------- host launcher ----------------
extern "C" void kernel_launch(void* const* d_in, const int* in_sizes, int n_in,
                              void* d_out, int out_size, void* d_ws, size_t ws_size,
                              hipStream_t stream) {
    (void)in_sizes; (void)n_in; (void)out_size;
    const float* x_in  = (const float*)d_in[0];
    const float* n1g   = (const float*)d_in[1];
    const float* n1b   = (const float*)d_in[2];
    const float* n2g   = (const float*)d_in[3];
    const float* n2b   = (const float*)d_in[4];
    const float* qkvw  = (const float*)d_in[5];
    const float* qbias = (const float*)d_in[6];
    const float* vbias = (const float*)d_in[7];
    const float* lscal = (const float*)d_in[8];
    const float* cpbw1 = (const float*)d_in[9];
    const float* cpbb1 = (const float*)d_in[10];
    const float* cpbw2 = (const float*)d_in[11];
    const float* projw = (const float*)d_in[12];
    const float* projb = (const float*)d_in[13];
    const float* fc1w  = (const float*)d_in[14];
    const float* fc1b  = (const float*)d_in[15];
    const float* fc2w  = (const float*)d_in[16];
    const float* fc2b  = (const float*)d_in[17];

    // residual stream X lives in d_out (fp32, MTOT*CDIM elements)
    float* X = (float*)d_out;

    // ---- ws layout: header 32 KB | bf16 weights (per depth) | chunk scratch ----
    float* RPB  = (float*)d_ws;                    // 1800 floats
    float* SCAL = RPB + 1800;                      // 8 floats
    float* QKVB = RPB + 1808;                      // 2304 floats (combined qkv bias)
    u16* Wq = (u16*)((char*)d_ws + 32768);         // 2304*768
    u16* Wp = Wq + 2304 * 768;                     // 768*768
    u16* W1 = Wp + 768 * 768;                      // 6144*768
    u16* W2 = W1 + 6144 * 768;                     // 768*3072
    u16* SCR = W2 + 768 * 3072;                    // chunk scratch

    // per-row scratch (uniform for both phases): 4608 u16 = 9216 B
    //  MLP : Xb(768) | Hg(3072) | Yc(768)
    //  attn: Xw(768) | QKV(2304)+OUTW(768) in Hg region | Yc(768)
    long long avail = (long long)ws_size - 32768 - 18874368;
    if (avail < 0) avail = 0;
    long long mc_ll = (avail / 9216) & ~255LL;
    int Mc = (int)(mc_ll < 256 ? 256 : (mc_ll > MTOT ? MTOT : mc_ll));

    u16* Xb   = SCR;                               // Mc*768
    u16* Hg   = Xb + (size_t)Mc * 768;             // Mc*3072
    u16* Yc   = Hg + (size_t)Mc * 3072;            // Mc*768
    u16* QKV  = Hg;                                // alias: Mc*2304
    u16* OUTW = Hg + (size_t)Mc * 2304;            // alias: Mc*768

    // copy input -> residual (fp32, 16B vectors)
    k_copy<<<(MTOT * CDIM) / 1024, 256, 0, stream>>>((const float4*)x_in, (float4*)X);

    for (int d = 0; d < 2; ++d) {
        int shift = d ? 4 : 0;
        // per-depth weight conversion to bf16 (tiny vs GEMM time)
        k_cvt<<<(2304*768/4 + 255)/256, 256, 0, stream>>>(
            (const float4*)(qkvw + (size_t)d * 2304 * 768), (ushort4*)Wq, 2304*768/4);
        k_cvt<<<(768*768/4 + 255)/256, 256, 0, stream>>>(
            (const float4*)(projw + (size_t)d * 768 * 768), (ushort4*)Wp, 768*768/4);
        k_cvt<<<(6144*768/4 + 255)/256, 256, 0, stream>>>(
            (const float4*)(fc1w + (size_t)d * 6144 * 768), (ushort4*)W1, 6144*768/4);
        k_cvt<<<(768*3072/4 + 255)/256, 256, 0, stream>>>(
            (const float4*)(fc2w + (size_t)d * 768 * 3072), (ushort4*)W2, 768*3072/4);
        k_qkvb<<<9, 256, 0, stream>>>(qbias + d * 768, vbias + d * 768, QKVB);
        k_cpb<<<1, 256, 0, stream>>>(cpbw1 + d * 1024, cpbb1 + d * 512,
                                     cpbw2 + d * 4096, lscal + d * 8, RPB, SCAL);
        // ---- attention branch, chunked (chunks touch disjoint X rows) ----
        for (int m0 = 0; m0 < MTOT; m0 += Mc) {
            int cur = (MTOT - m0) < Mc ? (MTOT - m0) : Mc;
            k_xcvt<<<cur, 192, 0, stream>>>(X, Xb, m0, shift, 1);
            k_mm128<0><<<dim3(2304 / 128, cur / 128), 256, 0, stream>>>(
                Xb, Wq, QKVB, QKV, 768, 2304);
            k_attn<<<(cur / 64) * NHEADS, 256, 0, stream>>>(QKV, RPB, SCAL, OUTW,
                                                            shift, m0 / 64);
            k_mm128<0><<<dim3(768 / 128, cur / 128), 256, 0, stream>>>(
                OUTW, Wp, projb + d * 768, Yc, 768, 768);
            k_ln_add<<<cur, 256, 0, stream>>>(X, Yc, n1g + d * 768, n1b + d * 768,
                                              m0, shift, 1);
        }
        // ---- MLP branch, chunked ----
        for (int m0 = 0; m0 < MTOT; m0 += Mc) {
            int cur = (MTOT - m0) < Mc ? (MTOT - m0) : Mc;
            k_xcvt<<<cur, 192, 0, stream>>>(X, Xb, m0, 0, 0);
            // gate half: Hg = gelu(X@Wg^T + bg)
            k_mm128<1><<<dim3(3072 / 128, cur / 128), 256, 0, stream>>>(
                Xb, W1, fc1b + d * 6144, Hg, 768, 3072);
            // val half: Hg *= (X@Wv^T + bv)
            k_mm128<2><<<dim3(3072 / 128, cur / 128), 256, 0, stream>>>(
                Xb, W1 + (size_t)3072 * 768, fc1b + d * 6144 + 3072, Hg, 768, 3072);
            k_mm128<0><<<dim3(768 / 128, cur / 128), 256, 0, stream>>>(
                Hg, W2, fc2b + d * 768, Yc, 3072, 768);
            k_ln_add<<<cur, 256, 0, stream>>>(X, Yc, n2g + d * 768, n2b + d * 768,
                                              m0, 0, 0);
        }
    }
}

// Round 7
// 3195.903 us; speedup vs baseline: 5.8166x; 1.2530x over previous
//
#include <hip/hip_runtime.h>
#include <hip/hip_bf16.h>
#include <math.h>

// ---------------- problem constants ----------------
#define HRES   64
#define WRES   128
#define CDIM   768
#define NHEADS 8
#define WINSZ  8
#define NTOK   64          // WINSZ*WINSZ
#define HDIM   96          // CDIM/NHEADS
#define HIDDIM 3072
#define NWH    8           // HRES/WINSZ
#define NWW    16          // WRES/WINSZ
#define NWIMG  128         // NWH*NWW
#define NWTOT  512         // B*NWIMG
#define MTOT   32768       // NWTOT*NTOK
#define CPBH   512

typedef unsigned short u16;
typedef __attribute__((ext_vector_type(8))) short bf16x8;   // 8 bf16 in 4 VGPRs
typedef __attribute__((ext_vector_type(4))) float f32x4;

__device__ __forceinline__ float bf2f(u16 u) {
    return __uint_as_float(((unsigned)u) << 16);
}
__device__ __forceinline__ u16 f2bf(float f) {
    unsigned u = __float_as_uint(f);
    u += 0x7FFFu + ((u >> 16) & 1u);
    return (u16)(u >> 16);
}
__device__ __forceinline__ float gelu_exact(float x) {
    return 0.5f * x * (1.0f + erff(x * 0.70710678118654752f));
}
__device__ __forceinline__ int reg_r(int r) { return r < HRES-8 ? 0 : (r < HRES-4 ? 1 : 2); }
__device__ __forceinline__ int reg_c(int c) { return c < WRES-8 ? 0 : (c < WRES-4 ? 1 : 2); }

// async global -> LDS, 16 bytes per lane; lds base must be wave-uniform
__device__ __forceinline__ void glds16(const u16* g, u16* l) {
    __builtin_amdgcn_global_load_lds(
        (const __attribute__((address_space(1))) void*)g,
        (__attribute__((address_space(3))) void*)l, 16, 0, 0);
}

// ---------------- fp32 copy input -> residual X (in d_out) ----------------
__global__ __launch_bounds__(256) void k_copy(const float4* __restrict__ in,
                                              float4* __restrict__ out) {
    size_t i = (size_t)blockIdx.x * 256 + threadIdx.x;
    out[i] = in[i];
}

// ---------------- generic fp32 -> bf16 conversion (weights) ----------------
__global__ __launch_bounds__(256) void k_cvt(const float4* __restrict__ in,
                                             ushort4* __restrict__ out, int n4) {
    int i = blockIdx.x * 256 + threadIdx.x;
    if (i < n4) {
        float4 v = in[i];
        ushort4 o;
        o.x = f2bf(v.x); o.y = f2bf(v.y); o.z = f2bf(v.z); o.w = f2bf(v.w);
        out[i] = o;
    }
}

// ---------------- build combined qkv bias (q | 0 | v), fp32 ----------------
__global__ __launch_bounds__(256) void k_qkvb(const float* __restrict__ qb,
                                              const float* __restrict__ vb,
                                              float* __restrict__ dst) {
    int i = blockIdx.x * 256 + threadIdx.x;
    if (i < 2304)
        dst[i] = (i < 768) ? qb[i] : ((i < 1536) ? 0.f : vb[i - 1536]);
}

// ---------------- X rows -> bf16 rows, optional shifted-window gather ----------------
__global__ __launch_bounds__(192) void k_xcvt(const float* __restrict__ X,
                                              u16* __restrict__ out,
                                              int m0, int shift, int winmap) {
    int lm = blockIdx.x, t = threadIdx.x;
    int gm = m0 + lm;
    int src;
    if (winmap) {
        int w = gm >> 6, n = gm & 63;
        int b = w >> 7, wim = w & 127, hi = wim >> 4, wi = wim & 15;
        int p = n >> 3, q = n & 7;
        int r  = (hi * 8 + p + shift) & (HRES - 1);
        int cc = (wi * 8 + q + shift) & (WRES - 1);
        src = (b * HRES + r) * WRES + cc;
    } else {
        src = gm;
    }
    float4 v = *(const float4*)(X + (size_t)src * CDIM + t * 4);
    ushort4 o;
    o.x = f2bf(v.x); o.y = f2bf(v.y); o.z = f2bf(v.z); o.w = f2bf(v.w);
    *(ushort4*)(out + (size_t)lm * CDIM + t * 4) = o;
}

// ---- CPB MLP, PARALLEL: 1800 one-wave blocks; lane l sums k=l..511 step 64 ----
// (round-4 PMC: single-block version was 415 us with 0.04% occupancy — 21% of
//  total runtime on 2.8 MFLOP. 1800 blocks x 8 coalesced iters + shfl reduce.)
__global__ __launch_bounds__(64) void k_cpb(const float* __restrict__ w1,
                                            const float* __restrict__ b1,
                                            const float* __restrict__ w2,
                                            const float* __restrict__ ls,
                                            float* __restrict__ rpb,
                                            float* __restrict__ scale) {
    int idx = blockIdx.x;            // 0..1799 = tt*8 + h
    int t = threadIdx.x;
    if (idx == 0 && t < NHEADS)
        scale[t] = __expf(fminf(ls[t], 4.6051701859880914f)); // ln(100)
    int tt = idx >> 3, h = idx & 7;
    int i = tt / 15, j = tt % 15;
    float vi = 8.0f * (float)(i - 7) / 7.0f;
    float vj = 8.0f * (float)(j - 7) / 7.0f;
    float si = (vi > 0.f) ? 1.f : ((vi < 0.f) ? -1.f : 0.f);
    float sj = (vj > 0.f) ? 1.f : ((vj < 0.f) ? -1.f : 0.f);
    float c0 = si * log2f(fabsf(vi) + 1.0f) * (1.0f / 3.0f);
    float c1 = sj * log2f(fabsf(vj) + 1.0f) * (1.0f / 3.0f);
    float sum = 0.f;
    #pragma unroll
    for (int k = t; k < CPBH; k += 64) {
        float hv = c0 * w1[2*k] + c1 * w1[2*k+1] + b1[k];
        if (hv > 0.f) sum += hv * w2[h * CPBH + k];
    }
    #pragma unroll
    for (int o = 32; o > 0; o >>= 1) sum += __shfl_xor(sum, o);
    if (t == 0) rpb[idx] = 16.0f / (1.0f + __expf(-sum));
}

// ======== 128x128 bf16 MFMA GEMM, dbuf + counted vmcnt, 2 blocks/CU ========
// C[M][N] = A[M][K] @ Bw[N][K]^T (+bias / gelu / in-place multiply).
// 256 threads = 4 waves, per-wave output 64x64 quadrant, BK=64.
// LDS 64 KB: As,Bs [2 dbuf][128 rows][64 bf16] -> 2 blocks/CU (TLP covers
// latency the 1-deep pipeline can't). 16B-block XOR swizzle as round 3
// (store G[r][s^(r&7)] via pre-swizzled GLOBAL block index, linear LDS dest;
// read block (fk|4+fk)^(r&7)) -> verified 0 bank conflicts.
// Counted-wait audit (same proof as round 3, which passed):
//   stage = exactly 8 glds16/wave; loop: STAGE(t+1,buf^1) -> vmcnt(8)
//   (completes ALL tile-t loads, only the 8 just issued remain) -> barrier ->
//   read/MFMA buf -> barrier. No load read in the phase it was staged.
// Epilogue: acc -> LDS (bf16) -> coalesced ushort8 row stores (full lines).
// Bijective XCD chunking (m204) for A-panel L2 locality.
template<int EPI>
__global__ __launch_bounds__(256, 2) void k_mm128(const u16* __restrict__ A,
                                                  const u16* __restrict__ Bw,
                                                  const float* __restrict__ bias,
                                                  u16* __restrict__ C,
                                                  int K, int N) {
    __shared__ __align__(16) u16 As[2][8192];   // [128][64] per buffer
    __shared__ __align__(16) u16 Bs[2][8192];
    int t = threadIdx.x;
    int l = t & 63, wv = t >> 6;
    // ---- bijective XCD chunk remap (consecutive HW ids share an XCD slab)
    int gx = gridDim.x;
    int nb = gx * gridDim.y;
    int b  = blockIdx.y * gx + blockIdx.x;
    int q8 = nb >> 3, r8 = nb & 7, x8 = b & 7, o8 = b >> 3;
    int v  = (x8 < r8 ? x8 * (q8 + 1) : r8 * (q8 + 1) + (x8 - r8) * q8) + o8;
    int tn = (v % gx) << 7, tm = (v / gx) << 7;
    // wave quadrant
    int wr = wv >> 1, wc = wv & 1;
    int r0 = wr << 6, c0 = wc << 6;
    int fr = l & 15, fk = l >> 4;
    // staging: wave wv covers rows [wv*32, wv*32+32), 4 issues of 8 rows each,
    // lane fetches global 16B-block (l&7)^(l>>3) -> linear LDS = swizzled store
    int lr8 = l >> 3;
    int kbs = (l & 7) ^ lr8;
    const u16* pA = A  + (size_t)(tm + wv * 32 + lr8) * K + kbs * 8;
    const u16* pB = Bw + (size_t)(tn + wv * 32 + lr8) * K + kbs * 8;
    // frag-read swizzled block offsets (u16 units)
    int rb0 = ((fk ^ (fr & 7)) << 3);
    int rb1 = (((4 + fk) ^ (fr & 7)) << 3);

    f32x4 acc[4][4];
    #pragma unroll
    for (int i = 0; i < 4; ++i)
        #pragma unroll
        for (int j = 0; j < 4; ++j)
            acc[i][j] = (f32x4){0.f, 0.f, 0.f, 0.f};
    bf16x8 Af[4][2], Bf[4][2];

    #define STG(arr, p, buf, h, kt) \
        glds16((p) + (size_t)((h) * 8) * K + (size_t)(kt) * 64, \
               &arr[buf][(wv << 11) + ((h) << 9)])
    #define STAGE_TILE(buf, kt) do { \
        STG(As, pA, buf, 0, kt); STG(As, pA, buf, 1, kt); \
        STG(As, pA, buf, 2, kt); STG(As, pA, buf, 3, kt); \
        STG(Bs, pB, buf, 0, kt); STG(Bs, pB, buf, 1, kt); \
        STG(Bs, pB, buf, 2, kt); STG(Bs, pB, buf, 3, kt); \
    } while (0)
    #define LDFRAG(buf) do { \
        _Pragma("unroll") \
        for (int ii = 0; ii < 4; ++ii) { \
            int roA = (r0 + ii * 16 + fr) << 6; \
            int roB = (c0 + ii * 16 + fr) << 6; \
            Af[ii][0] = *(const bf16x8*)&As[buf][roA + rb0]; \
            Af[ii][1] = *(const bf16x8*)&As[buf][roA + rb1]; \
            Bf[ii][0] = *(const bf16x8*)&Bs[buf][roB + rb0]; \
            Bf[ii][1] = *(const bf16x8*)&Bs[buf][roB + rb1]; \
        } } while (0)
    #define MEMBAR() do { asm volatile("" ::: "memory"); \
        __builtin_amdgcn_s_barrier(); \
        asm volatile("" ::: "memory"); } while (0)

    STAGE_TILE(0, 0);
    int NK = K >> 6;
    for (int kt = 0; kt < NK; ++kt) {
        int cur = kt & 1;
        if (kt + 1 < NK) {
            STAGE_TILE(cur ^ 1, kt + 1);
            asm volatile("s_waitcnt vmcnt(8)" ::: "memory");
        } else {
            asm volatile("s_waitcnt vmcnt(0)" ::: "memory");
        }
        MEMBAR();                       // tile kt fully visible to all waves
        LDFRAG(cur);
        __builtin_amdgcn_s_setprio(1);
        #pragma unroll
        for (int ii = 0; ii < 4; ++ii)
            #pragma unroll
            for (int jj = 0; jj < 4; ++jj)
                #pragma unroll
                for (int ks = 0; ks < 2; ++ks)
                    acc[ii][jj] = __builtin_amdgcn_mfma_f32_16x16x32_bf16(
                        Af[ii][ks], Bf[jj][ks], acc[ii][jj], 0, 0, 0);
        __builtin_amdgcn_s_setprio(0);
        MEMBAR();                       // all reads of buf done before overwrite
    }
    #undef STG
    #undef STAGE_TILE
    #undef LDFRAG
    #undef MEMBAR

    // ---- epilogue: acc -> LDS (bf16 tile [128][128]) -> coalesced stores ----
    // C/D layout: col = lane&15, row = (lane>>4)*4 + reg  [verified m89]
    u16* Cs = (u16*)As;   // 32 KB = 128*128 u16, safe: loop ended with barrier
    float bj[4];
    #pragma unroll
    for (int j = 0; j < 4; ++j) bj[j] = bias[tn + c0 + j * 16 + fr];
    #pragma unroll
    for (int i = 0; i < 4; ++i) {
        int row = r0 + i * 16 + (fk << 2);
        #pragma unroll
        for (int j = 0; j < 4; ++j) {
            int col = c0 + j * 16 + fr;
            #pragma unroll
            for (int r = 0; r < 4; ++r) {
                float vv = acc[i][j][r] + bj[j];
                if (EPI == 1) vv = gelu_exact(vv);
                Cs[(row + r) * 128 + col] = f2bf(vv);
            }
        }
    }
    __syncthreads();
    #pragma unroll
    for (int p = 0; p < 8; ++p) {
        int idx = p * 2048 + t * 8;
        int row = idx >> 7, col = idx & 127;
        ushort4 lo = *(const ushort4*)&Cs[idx];
        ushort4 hi = *(const ushort4*)&Cs[idx + 4];
        u16* gp = &C[(size_t)(tm + row) * N + tn + col];
        if (EPI == 2) {
            ushort4 ol = *(const ushort4*)gp;
            ushort4 oh = *(const ushort4*)(gp + 4);
            lo.x = f2bf(bf2f(ol.x) * bf2f(lo.x)); lo.y = f2bf(bf2f(ol.y) * bf2f(lo.y));
            lo.z = f2bf(bf2f(ol.z) * bf2f(lo.z)); lo.w = f2bf(bf2f(ol.w) * bf2f(lo.w));
            hi.x = f2bf(bf2f(oh.x) * bf2f(hi.x)); hi.y = f2bf(bf2f(oh.y) * bf2f(hi.y));
            hi.z = f2bf(bf2f(oh.z) * bf2f(hi.z)); hi.w = f2bf(bf2f(oh.w) * bf2f(hi.w));
        }
        *(ushort4*)gp       = lo;
        *(ushort4*)(gp + 4) = hi;
    }
}

// ---------------- fused attention per (window, head); bf16 in/out ----------------
__global__ __launch_bounds__(256) void k_attn(const u16* __restrict__ QKV,
                                              const float* __restrict__ rpb,
                                              const float* __restrict__ scale,
                                              u16* __restrict__ outw,
                                              int shift, int w0) {
    __shared__ float smQ[64][100];   // q, later reused for v (pad 100: float4-aligned rows)
    __shared__ float smK[64][100];
    int wl = blockIdx.x >> 3;       // local window
    int wg = w0 + wl;               // global window (for mask region)
    int h = blockIdx.x & 7;
    int t = threadIdx.x;
    const u16* base = QKV + (size_t)wl * NTOK * 2304 + h * HDIM;
    for (int i4 = t; i4 < NTOK * 24; i4 += 256) {
        int nn = i4 / 24, jj = (i4 % 24) * 4;
        const u16* rq = base + (size_t)nn * 2304 + jj;
        ushort4 uq = *(const ushort4*)rq;
        ushort4 uk = *(const ushort4*)(rq + 768);
        float4 fq, fk4;
        fq.x = bf2f(uq.x); fq.y = bf2f(uq.y); fq.z = bf2f(uq.z); fq.w = bf2f(uq.w);
        fk4.x = bf2f(uk.x); fk4.y = bf2f(uk.y); fk4.z = bf2f(uk.z); fk4.w = bf2f(uk.w);
        *(float4*)&smQ[nn][jj] = fq;
        *(float4*)&smK[nn][jj] = fk4;
    }
    __syncthreads();
    if (t < 128) {
        int row = t & 63;
        float4* rp4 = (t < 64) ? (float4*)smQ[row] : (float4*)smK[row];
        float ss = 0.f;
        #pragma unroll
        for (int jj = 0; jj < 24; ++jj) {
            float4 v = rp4[jj];
            ss += v.x * v.x + v.y * v.y + v.z * v.z + v.w * v.w;
        }
        float rn = 1.0f / fmaxf(sqrtf(ss), 1e-12f);
        if (t < 64) rn *= scale[h];
        #pragma unroll
        for (int jj = 0; jj < 24; ++jj) {
            float4 v = rp4[jj];
            v.x *= rn; v.y *= rn; v.z *= rn; v.w *= rn;
            rp4[jj] = v;
        }
    }
    __syncthreads();
    int n = t >> 2, m0q = (t & 3) << 4;
    int p1 = n >> 3, q1 = n & 7;
    int idn = 0, hi = 0, wi = 0;
    if (shift) {
        int wim = wg & 127; hi = wim >> 4; wi = wim & 15;
        idn = reg_r(hi * 8 + p1) * 3 + reg_c(wi * 8 + q1);
    }
    float4 qv[24];
    #pragma unroll
    for (int jj = 0; jj < 24; ++jj) qv[jj] = *(const float4*)&smQ[n][jj * 4];
    float P[16];
    #pragma unroll 1
    for (int s = 0; s < 16; ++s) {
        int mm = m0q + s;
        const float4* kr = (const float4*)&smK[mm][0];
        float acc = 0.f;
        #pragma unroll
        for (int jj = 0; jj < 24; ++jj) {
            float4 a = qv[jj], b = kr[jj];
            acc = fmaf(a.x, b.x, acc); acc = fmaf(a.y, b.y, acc);
            acc = fmaf(a.z, b.z, acc); acc = fmaf(a.w, b.w, acc);
        }
        int p2 = mm >> 3, q2 = mm & 7;
        acc += rpb[((p1 - p2 + 7) * 15 + (q1 - q2 + 7)) * NHEADS + h];
        if (shift) {
            int idm = reg_r(hi * 8 + p2) * 3 + reg_c(wi * 8 + q2);
            if (idm != idn) acc -= 100.0f;
        }
        P[s] = acc;
    }
    float mx = P[0];
    #pragma unroll
    for (int s = 1; s < 16; ++s) mx = fmaxf(mx, P[s]);
    mx = fmaxf(mx, __shfl_xor(mx, 1));
    mx = fmaxf(mx, __shfl_xor(mx, 2));
    float sum = 0.f;
    #pragma unroll
    for (int s = 0; s < 16; ++s) { P[s] = __expf(P[s] - mx); sum += P[s]; }
    sum += __shfl_xor(sum, 1);
    sum += __shfl_xor(sum, 2);
    float inv = 1.0f / sum;
    #pragma unroll
    for (int s = 0; s < 16; ++s) P[s] *= inv;
    __syncthreads();   // done reading q
    for (int i4 = t; i4 < NTOK * 24; i4 += 256) {
        int nn = i4 / 24, jj = (i4 % 24) * 4;
        ushort4 uv = *(const ushort4*)(base + (size_t)nn * 2304 + 1536 + jj);
        float4 fv;
        fv.x = bf2f(uv.x); fv.y = bf2f(uv.y); fv.z = bf2f(uv.z); fv.w = bf2f(uv.w);
        *(float4*)&smQ[nn][jj] = fv;   // v
    }
    __syncthreads();
    u16* orow = outw + ((size_t)wl * NTOK + n) * CDIM + h * HDIM;
    #pragma unroll 1
    for (int c0 = 0; c0 < HDIM; c0 += 24) {
        float4 part[6];
        #pragma unroll
        for (int jj = 0; jj < 6; ++jj) { part[jj].x = 0.f; part[jj].y = 0.f; part[jj].z = 0.f; part[jj].w = 0.f; }
        #pragma unroll 1
        for (int s = 0; s < 16; ++s) {
            float pv = P[s];
            const float4* vr = (const float4*)&smQ[m0q + s][c0];
            #pragma unroll
            for (int jj = 0; jj < 6; ++jj) {
                float4 v4 = vr[jj];
                part[jj].x = fmaf(pv, v4.x, part[jj].x);
                part[jj].y = fmaf(pv, v4.y, part[jj].y);
                part[jj].z = fmaf(pv, v4.z, part[jj].z);
                part[jj].w = fmaf(pv, v4.w, part[jj].w);
            }
        }
        #pragma unroll
        for (int jj = 0; jj < 6; ++jj) {
            part[jj].x += __shfl_xor(part[jj].x, 1); part[jj].x += __shfl_xor(part[jj].x, 2);
            part[jj].y += __shfl_xor(part[jj].y, 1); part[jj].y += __shfl_xor(part[jj].y, 2);
            part[jj].z += __shfl_xor(part[jj].z, 1); part[jj].z += __shfl_xor(part[jj].z, 2);
            part[jj].w += __shfl_xor(part[jj].w, 1); part[jj].w += __shfl_xor(part[jj].w, 2);
        }
        if ((t & 3) == (c0 / 24)) {
            u16 tmp[24];
            #pragma unroll
            for (int jj = 0; jj < 6; ++jj) {
                tmp[jj*4+0] = f2bf(part[jj].x); tmp[jj*4+1] = f2bf(part[jj].y);
                tmp[jj*4+2] = f2bf(part[jj].z); tmp[jj*4+3] = f2bf(part[jj].w);
            }
            *(uint4*)&orow[c0]      = *(const uint4*)&tmp[0];
            *(uint4*)&orow[c0 + 8]  = *(const uint4*)&tmp[8];
            *(uint4*)&orow[c0 + 16] = *(const uint4*)&tmp[16];
        }
    }
}

// ---------------- chunked LayerNorm + residual: X[target] += LN(Yc[lm])*g + b ----------------
__global__ __launch_bounds__(256) void k_ln_add(float* __restrict__ X,
                                                const u16* __restrict__ Yc,
                                                const float* __restrict__ g,
                                                const float* __restrict__ bb,
                                                int m0, int shift, int winmap) {
    int lm = blockIdx.x;
    int gm = m0 + lm;
    int target;
    if (winmap) {
        int w = gm >> 6, n = gm & 63;
        int b = w >> 7, wim = w & 127, hi = wim >> 4, wi = wim & 15;
        int p = n >> 3, q = n & 7;
        int r  = (hi * 8 + p + shift) & (HRES - 1);
        int cc = (wi * 8 + q + shift) & (WRES - 1);
        target = (b * HRES + r) * WRES + cc;
    } else {
        target = gm;
    }
    size_t xo = (size_t)target * CDIM;
    size_t yo = (size_t)lm * CDIM;
    int t = threadIdx.x;
    float v0 = bf2f(Yc[yo + t]), v1 = bf2f(Yc[yo + t + 256]), v2 = bf2f(Yc[yo + t + 512]);
    float s = v0 + v1 + v2;
    float ss = v0*v0 + v1*v1 + v2*v2;
    #pragma unroll
    for (int o = 32; o > 0; o >>= 1) {
        s  += __shfl_down(s, o);
        ss += __shfl_down(ss, o);
    }
    __shared__ float rs_[4], rss_[4];
    if ((t & 63) == 0) { rs_[t >> 6] = s; rss_[t >> 6] = ss; }
    __syncthreads();
    float S  = rs_[0] + rs_[1] + rs_[2] + rs_[3];
    float SS = rss_[0] + rss_[1] + rss_[2] + rss_[3];
    float mu = S * (1.0f / CDIM);
    float var = SS * (1.0f / CDIM) - mu * mu;
    float rstd = rsqrtf(fmaxf(var, 0.0f) + 1e-5f);
    X[xo + t]       += (v0 - mu) * rstd * g[t]       + bb[t];
    X[xo + t + 256] += (v1 - mu) * rstd * g[t + 256] + bb[t + 256];
    X[xo + t + 512] += (v2 - mu) * rstd * g[t + 512] + bb[t + 512];
}

// ---------------- host launcher ----------------
extern "C" void kernel_launch(void* const* d_in, const int* in_sizes, int n_in,
                              void* d_out, int out_size, void* d_ws, size_t ws_size,
                              hipStream_t stream) {
    (void)in_sizes; (void)n_in; (void)out_size;
    const float* x_in  = (const float*)d_in[0];
    const float* n1g   = (const float*)d_in[1];
    const float* n1b   = (const float*)d_in[2];
    const float* n2g   = (const float*)d_in[3];
    const float* n2b   = (const float*)d_in[4];
    const float* qkvw  = (const float*)d_in[5];
    const float* qbias = (const float*)d_in[6];
    const float* vbias = (const float*)d_in[7];
    const float* lscal = (const float*)d_in[8];
    const float* cpbw1 = (const float*)d_in[9];
    const float* cpbb1 = (const float*)d_in[10];
    const float* cpbw2 = (const float*)d_in[11];
    const float* projw = (const float*)d_in[12];
    const float* projb = (const float*)d_in[13];
    const float* fc1w  = (const float*)d_in[14];
    const float* fc1b  = (const float*)d_in[15];
    const float* fc2w  = (const float*)d_in[16];
    const float* fc2b  = (const float*)d_in[17];

    // residual stream X lives in d_out (fp32, MTOT*CDIM elements)
    float* X = (float*)d_out;

    // ---- ws layout: header 32 KB | bf16 weights (per depth) | chunk scratch ----
    float* RPB  = (float*)d_ws;                    // 1800 floats
    float* SCAL = RPB + 1800;                      // 8 floats
    float* QKVB = RPB + 1808;                      // 2304 floats (combined qkv bias)
    u16* Wq = (u16*)((char*)d_ws + 32768);         // 2304*768
    u16* Wp = Wq + 2304 * 768;                     // 768*768
    u16* W1 = Wp + 768 * 768;                      // 6144*768
    u16* W2 = W1 + 6144 * 768;                     // 768*3072
    u16* SCR = W2 + 768 * 3072;                    // chunk scratch

    // per-row scratch (uniform for both phases): 4608 u16 = 9216 B
    //  MLP : Xb(768) | Hg(3072) | Yc(768)
    //  attn: Xw(768) | QKV(2304)+OUTW(768) in Hg region | Yc(768)
    long long avail = (long long)ws_size - 32768 - 18874368;
    if (avail < 0) avail = 0;
    long long mc_ll = (avail / 9216) & ~255LL;
    int Mc = (int)(mc_ll < 256 ? 256 : (mc_ll > MTOT ? MTOT : mc_ll));

    u16* Xb   = SCR;                               // Mc*768
    u16* Hg   = Xb + (size_t)Mc * 768;             // Mc*3072
    u16* Yc   = Hg + (size_t)Mc * 3072;            // Mc*768
    u16* QKV  = Hg;                                // alias: Mc*2304
    u16* OUTW = Hg + (size_t)Mc * 2304;            // alias: Mc*768

    // copy input -> residual (fp32, 16B vectors)
    k_copy<<<(MTOT * CDIM) / 1024, 256, 0, stream>>>((const float4*)x_in, (float4*)X);

    for (int d = 0; d < 2; ++d) {
        int shift = d ? 4 : 0;
        // per-depth weight conversion to bf16 (tiny vs GEMM time)
        k_cvt<<<(2304*768/4 + 255)/256, 256, 0, stream>>>(
            (const float4*)(qkvw + (size_t)d * 2304 * 768), (ushort4*)Wq, 2304*768/4);
        k_cvt<<<(768*768/4 + 255)/256, 256, 0, stream>>>(
            (const float4*)(projw + (size_t)d * 768 * 768), (ushort4*)Wp, 768*768/4);
        k_cvt<<<(6144*768/4 + 255)/256, 256, 0, stream>>>(
            (const float4*)(fc1w + (size_t)d * 6144 * 768), (ushort4*)W1, 6144*768/4);
        k_cvt<<<(768*3072/4 + 255)/256, 256, 0, stream>>>(
            (const float4*)(fc2w + (size_t)d * 768 * 3072), (ushort4*)W2, 768*3072/4);
        k_qkvb<<<9, 256, 0, stream>>>(qbias + d * 768, vbias + d * 768, QKVB);
        k_cpb<<<1800, 64, 0, stream>>>(cpbw1 + d * 1024, cpbb1 + d * 512,
                                       cpbw2 + d * 4096, lscal + d * 8, RPB, SCAL);
        // ---- attention branch, chunked (chunks touch disjoint X rows) ----
        for (int m0 = 0; m0 < MTOT; m0 += Mc) {
            int cur = (MTOT - m0) < Mc ? (MTOT - m0) : Mc;
            k_xcvt<<<cur, 192, 0, stream>>>(X, Xb, m0, shift, 1);
            k_mm128<0><<<dim3(2304 / 128, cur / 128), 256, 0, stream>>>(
                Xb, Wq, QKVB, QKV, 768, 2304);
            k_attn<<<(cur / 64) * NHEADS, 256, 0, stream>>>(QKV, RPB, SCAL, OUTW,
                                                            shift, m0 / 64);
            k_mm128<0><<<dim3(768 / 128, cur / 128), 256, 0, stream>>>(
                OUTW, Wp, projb + d * 768, Yc, 768, 768);
            k_ln_add<<<cur, 256, 0, stream>>>(X, Yc, n1g + d * 768, n1b + d * 768,
                                              m0, shift, 1);
        }
        // ---- MLP branch, chunked ----
        for (int m0 = 0; m0 < MTOT; m0 += Mc) {
            int cur = (MTOT - m0) < Mc ? (MTOT - m0) : Mc;
            k_xcvt<<<cur, 192, 0, stream>>>(X, Xb, m0, 0, 0);
            // gate half: Hg = gelu(X@Wg^T + bg)
            k_mm128<1><<<dim3(3072 / 128, cur / 128), 256, 0, stream>>>(
                Xb, W1, fc1b + d * 6144, Hg, 768, 3072);
            // val half: Hg *= (X@Wv^T + bv)
            k_mm128<2><<<dim3(3072 / 128, cur / 128), 256, 0, stream>>>(
                Xb, W1 + (size_t)3072 * 768, fc1b + d * 6144 + 3072, Hg, 768, 3072);
            k_mm128<0><<<dim3(768 / 128, cur / 128), 256, 0, stream>>>(
                Hg, W2, fc2b + d * 768, Yc, 3072, 768);
            k_ln_add<<<cur, 256, 0, stream>>>(X, Yc, n2g + d * 768, n2b + d * 768,
                                              m0, 0, 0);
        }
    }
}